// Round 17
// baseline (458.217 us; speedup 1.0000x reference)
//
#include <hip/hip_runtime.h>
#include <cstdint>

// Problem constants
#define B_   4
#define S_   2048
#define D_   1024
#define H_   16
#define HD_  64
#define FF_  4096
#define MTOK 8192   // B_*S_

// may_alias: these type-pun LDS/global u16 buffers; without it TBAA treats
// short8-loads vs ushort-stores as no-alias and reorders them (round-2 NaN).
typedef short s16x8 __attribute__((ext_vector_type(8), may_alias));
typedef float f32x4 __attribute__((ext_vector_type(4)));
typedef float f32x16 __attribute__((ext_vector_type(16)));
typedef unsigned short u16x4 __attribute__((ext_vector_type(4), may_alias));
typedef unsigned short u16x8 __attribute__((ext_vector_type(8), may_alias));

// async global->LDS, 16B per lane (used by k_attn staging)
#define GLD_LDS16(g, l)                                                  \
  __builtin_amdgcn_global_load_lds(                                      \
      (__attribute__((address_space(1))) void*)(g),                      \
      (__attribute__((address_space(3))) void*)(l), 16, 0, 0)

__device__ __forceinline__ unsigned short f2bf(float f) {
  unsigned u = __float_as_uint(f);
  unsigned r = 0x7fffu + ((u >> 16) & 1u);   // RNE
  return (unsigned short)((u + r) >> 16);
}

// ---------------- weight transpose + fp32->bf16 ----------------
__global__ __launch_bounds__(256) void k_transpose(const float* __restrict__ in,
                                                   unsigned short* __restrict__ out,
                                                   int R, int C) {
  __shared__ float tile[32][33];
  int tx = threadIdx.x, ty = threadIdx.y;             // 32 x 8
  int c0 = blockIdx.x * 32, r0 = blockIdx.y * 32;
#pragma unroll
  for (int j = 0; j < 4; ++j)
    tile[ty + j * 8][tx] = in[(size_t)(r0 + ty + j * 8) * C + (c0 + tx)];
  __syncthreads();
#pragma unroll
  for (int j = 0; j < 4; ++j)
    out[(size_t)(c0 + ty + j * 8) * R + (r0 + tx)] = f2bf(tile[tx][ty + j * 8]);
}

// ---------------- LayerNorm (D=1024, one block per row) ----------------
__global__ __launch_bounds__(256) void k_layernorm(const float* __restrict__ x,
                                                   const float* __restrict__ g,
                                                   const float* __restrict__ be,
                                                   unsigned short* __restrict__ out) {
  int row = blockIdx.x, t = threadIdx.x;
  const float4* xr = (const float4*)(x + (size_t)row * D_);
  float4 v = xr[t];
  float s = v.x + v.y + v.z + v.w;
  float q = v.x * v.x + v.y * v.y + v.z * v.z + v.w * v.w;
#pragma unroll
  for (int o = 1; o < 64; o <<= 1) { s += __shfl_xor(s, o); q += __shfl_xor(q, o); }
  __shared__ float red[8];
  int wid = t >> 6;
  if ((t & 63) == 0) { red[wid * 2] = s; red[wid * 2 + 1] = q; }
  __syncthreads();
  s = red[0] + red[2] + red[4] + red[6];
  q = red[1] + red[3] + red[5] + red[7];
  float mean = s * (1.0f / D_);
  float rstd = rsqrtf(q * (1.0f / D_) - mean * mean + 1e-5f);
  float4 gv = ((const float4*)g)[t];
  float4 bv = ((const float4*)be)[t];
  u16x4 o4;
  o4[0] = f2bf(gv.x * (v.x - mean) * rstd + bv.x);
  o4[1] = f2bf(gv.y * (v.y - mean) * rstd + bv.y);
  o4[2] = f2bf(gv.z * (v.z - mean) * rstd + bv.z);
  o4[3] = f2bf(gv.w * (v.w - mean) * rstd + bv.w);
  *(u16x4*)(out + (size_t)row * D_ + t * 4) = o4;
}

// ---------------- GEMM: C = A[M][K] * Bt[N][K]^T (32x32x16 MFMA) ----------
// Round-17: SAME r16 skeleton (reg-staged, double-buffered, L2 group swizzle)
// with the math width changed to v_mfma_f32_32x32x16_bf16: HALF the MFMA
// instruction count per FLOP (32.8 vs 16.4 KFLOP/inst) and a higher measured
// ceiling (2382 vs 2075 TF). Tests the "time ~ MFMA inst count @ fixed 5x
// multiplier" theory that survived rounds 9-16's memory-side eliminations.
// Wave-tile 64x64 = 2x2 32x32 frags (acc f32x16[2][2]); per K-step(64): 4
// k-slices x (2 A + 2 B b128 reads + 4 MFMAs) = 16 reads, 16 MFMAs.
// 32-row fragment reads have structural ~4-way bank aliasing at 128B rows
// (3-bit chunk entropy vs 5-bit row index) -- accepted; SQ_LDS_BANK_CONFLICT
// going nonzero is expected and diagnostic.
// Input frag layout (extension of verified 16x16x32 mapping): lane l holds
// row/col = l&31, k = (l>>5)*8 + j, j=0..7. C/D (HW-verified m74/m101):
// col = l&31, row = (reg&3) + 8*(reg>>2) + 4*(l>>5), reg in [0,16).
// MODE 1: +bias, GELU(exp2) -> bf16; MODE 2: +bias,+f32 resid -> f32;
// MODE 3: fused QKV: Q*0.125 | K | V-transposed-per-head.
template <int MODE, int GN, int GM>
__global__ __launch_bounds__(512, 2) void k_gemmdp(
    const unsigned short* __restrict__ A, const unsigned short* __restrict__ Bt,
    const float* __restrict__ bias, const float* __restrict__ resid,
    unsigned short* __restrict__ outb, float* __restrict__ outf,
    int M, int N, int K) {
  constexpr int BM = 128, BN = 256, BK = 64;
  constexpr int AE = BM * BK;            // 8192 u16 (16KB)
  constexpr int BE = BN * BK;            // 16384 u16 (32KB)
  constexpr int BUF_E = AE + BE;         // 24576 u16 (48KB)
  __shared__ __align__(16) unsigned short smem[2 * BUF_E];   // 96KB
  unsigned short* const Rs = smem;       // epilogue overlay [64][264]

  const int tid = threadIdx.x;
  const int wid = tid >> 6, lane = tid & 63;
  const int l32 = lane & 31, lh = lane >> 5;   // 32-lane row, k-half
  const int wr = wid >> 2, wc = wid & 3;       // 2M x 4N waves
  // L2-resident group swizzle (round 15): XCD chunk -> GN x GM tile groups.
  constexpr int GSZ = GN * GM;
  const int nwg = gridDim.x * gridDim.y;
  const int id = blockIdx.y * gridDim.x + blockIdx.x;
  const int chunk = nwg >> 3;
  const int xcd = id & 7, s = id >> 3;
  const int gpx = s / GSZ + xcd * (chunk / GSZ);
  const int r = s % GSZ;
  const int ngx = gridDim.x / GN;
  const int gx = gpx % ngx, gy = gpx / ngx;
  const int n0 = (gx * GN + (r % GN)) * BN;
  const int m0 = (gy * GM + (r / GN)) * BM;

  f32x16 acc[2][2];
#pragma unroll
  for (int m = 0; m < 2; ++m)
#pragma unroll
    for (int n = 0; n < 2; ++n) acc[m][n] = (f32x16)0.0f;

  // reg-staging (r16): thread q=g*512+tid -> row q>>3, chunk c=q&7; global
  // source LINEAR; LDS write offset carries the 3-bit XOR swizzle (16B
  // aligned by construction).
  const unsigned short* aSrcL[2]; int aWOff[2];
  const unsigned short* bSrcL[4]; int bWOff[4];
#pragma unroll
  for (int g = 0; g < 2; ++g) {
    int q = g * 512 + tid, row = q >> 3, c = q & 7;
    aSrcL[g] = A + (size_t)(m0 + row) * K + c * 8;
    aWOff[g] = row * BK + ((c ^ (row & 7)) << 3);
  }
#pragma unroll
  for (int g = 0; g < 4; ++g) {
    int q = g * 512 + tid, row = q >> 3, c = q & 7;
    bSrcL[g] = Bt + (size_t)(n0 + row) * K + c * 8;
    bWOff[g] = row * BK + ((c ^ (row & 7)) << 3);
  }
  // fragment reads: row = (wave base) + l32; k-chunk for slice ks:
  // c = 2*ks + lh, swizzled by row&7 == l32&7.
  int cSw[4];
#pragma unroll
  for (int ks = 0; ks < 4; ++ks) cSw[ks] = ((2 * ks + lh) ^ (l32 & 7)) * 8;
  const int aRow0 = (wr * 64 + l32) * BK;          // + mf*32*BK
  const int bRow0 = (wc * 64 + l32) * BK;          // + nf*32*BK

#define LOADG(R, ti)                                                           \
  {                                                                            \
    const int _kt = (ti) * BK;                                                 \
    _Pragma("unroll")                                                          \
    for (int g = 0; g < 2; ++g) R[g] = *(const u16x8*)(aSrcL[g] + _kt);        \
    _Pragma("unroll")                                                          \
    for (int g = 0; g < 4; ++g) R[2 + g] = *(const u16x8*)(bSrcL[g] + _kt);    \
  }
#define DSWRITE(R, BUF)                                                        \
  {                                                                            \
    unsigned short* _pa = smem + (BUF) * BUF_E;                                \
    unsigned short* _pb = _pa + AE;                                            \
    _Pragma("unroll")                                                          \
    for (int g = 0; g < 2; ++g) *(u16x8*)(_pa + aWOff[g]) = R[g];              \
    _Pragma("unroll")                                                          \
    for (int g = 0; g < 4; ++g) *(u16x8*)(_pb + bWOff[g]) = R[2 + g];          \
  }
#define COMPUTE(BUF)                                                           \
  {                                                                            \
    const unsigned short* pa = smem + (BUF) * BUF_E + aRow0;                   \
    const unsigned short* pb = smem + (BUF) * BUF_E + AE + bRow0;              \
    _Pragma("unroll")                                                          \
    for (int ks = 0; ks < 4; ++ks) {                                           \
      s16x8 af0 = *(const s16x8*)(pa + cSw[ks]);                               \
      s16x8 af1 = *(const s16x8*)(pa + 32 * BK + cSw[ks]);                     \
      s16x8 bf0 = *(const s16x8*)(pb + cSw[ks]);                               \
      s16x8 bf1 = *(const s16x8*)(pb + 32 * BK + cSw[ks]);                     \
      __builtin_amdgcn_s_setprio(1);                                           \
      acc[0][0] = __builtin_amdgcn_mfma_f32_32x32x16_bf16(af0, bf0, acc[0][0], 0, 0, 0); \
      acc[0][1] = __builtin_amdgcn_mfma_f32_32x32x16_bf16(af0, bf1, acc[0][1], 0, 0, 0); \
      acc[1][0] = __builtin_amdgcn_mfma_f32_32x32x16_bf16(af1, bf0, acc[1][0], 0, 0, 0); \
      acc[1][1] = __builtin_amdgcn_mfma_f32_32x32x16_bf16(af1, bf1, acc[1][1], 0, 0, 0); \
      __builtin_amdgcn_s_setprio(0);                                           \
    }                                                                          \
  }

  const int nt = K / BK;                     // 16 or 64 (even)
  u16x8 rA[6], rB[6];
  LOADG(rA, 0)
  DSWRITE(rA, 0)                             // compiler waits rA's vmcnt here
  __syncthreads();
  LOADG(rB, 1)

  for (int i = 0; i < nt; i += 2) {
    if (i + 2 < nt) LOADG(rA, i + 2)
    COMPUTE(0)
    DSWRITE(rB, 1)
    __syncthreads();
    if (i + 3 < nt) LOADG(rB, i + 3)
    COMPUTE(1)
    if (i + 2 < nt) {
      DSWRITE(rA, 0)
      __syncthreads();
    }
  }
#undef LOADG
#undef DSWRITE
#undef COMPUTE

  // ---------------- epilogues (32x32 C/D layout) ----------------
  // row_in(reg) = (reg&3) + 8*(reg>>2) + 4*lh;  col_in = l32.
  if constexpr (MODE == 2) {
#pragma unroll
    for (int nf = 0; nf < 2; ++nf) {
      const int col = n0 + wc * 64 + nf * 32 + l32;
      const float bv = bias[col];
#pragma unroll
      for (int mf = 0; mf < 2; ++mf)
#pragma unroll
        for (int rg = 0; rg < 16; ++rg) {
          const int row = m0 + wr * 64 + mf * 32 + (rg & 3) + 8 * (rg >> 2) + 4 * lh;
          outf[(size_t)row * N + col] = acc[mf][nf][rg] + bv + resid[(size_t)row * N + col];
        }
    }
    return;
  }

  __syncthreads();                           // Rs overlays staging LDS
  // Row-major bf16 repack: Rs[64][264] per 64-row pass -> coalesced u16x8.
#define ROWMAJOR_FLUSH(DSTPTR, NSTRIDE, COLBASE, XFORM)                        \
  {                                                                            \
    _Pragma("unroll")                                                          \
    for (int p = 0; p < 2; ++p) {                                              \
      if (wr == p) {                                                           \
        _Pragma("unroll")                                                      \
        for (int nf = 0; nf < 2; ++nf) {                                       \
          const int col = wc * 64 + nf * 32 + l32;                             \
          _Pragma("unroll")                                                    \
          for (int mf = 0; mf < 2; ++mf) {                                     \
            _Pragma("unroll")                                                  \
            for (int rg = 0; rg < 16; ++rg) {                                  \
              float xv = acc[mf][nf][rg];                                      \
              XFORM;                                                           \
              Rs[(mf * 32 + (rg & 3) + 8 * (rg >> 2) + 4 * lh) * 264 + col] = f2bf(xv); \
            }                                                                  \
          }                                                                    \
        }                                                                      \
      }                                                                        \
      __syncthreads();                                                         \
      const int row_l = tid >> 3;                                              \
      _Pragma("unroll")                                                        \
      for (int j = 0; j < 4; ++j) {                                            \
        const int c = (tid & 7) * 4 + j;                                       \
        u16x8 vv = *(const u16x8*)(Rs + row_l * 264 + c * 8);                  \
        *(u16x8*)((DSTPTR) + (size_t)(m0 + p * 64 + row_l) * (NSTRIDE) +       \
                  (COLBASE) + c * 8) = vv;                                     \
      }                                                                        \
      if (p == 0) __syncthreads();                                             \
    }                                                                          \
  }

  if constexpr (MODE == 1) {
    // gelu(x) = x * rcp(1 + exp2(-2u*log2e)), exact tanh form
    ROWMAJOR_FLUSH(outb, N, n0, {
      xv += bias[n0 + col];
      float uu = 0.7978845608028654f * (xv + 0.044715f * xv * xv * xv);
      xv = xv * __builtin_amdgcn_rcpf(1.0f + __builtin_amdgcn_exp2f(uu * -2.885390081777927f));
    });
    return;
  }

  if constexpr (MODE == 3) {
    unsigned short* qout = outb;
    unsigned short* kout = outb + (size_t)MTOK * D_;
    unsigned short* vout = outb + 2 * (size_t)MTOK * D_;
    if (n0 < 1024) {
      ROWMAJOR_FLUSH(qout, D_, n0, { xv *= 0.125f; });
    } else if (n0 < 2048) {
      ROWMAJOR_FLUSH(kout, D_, n0 - 1024, {});
    } else {
      // V transposed [hd][s]: 4 hd-groups of 64 (group g owned by wc==g).
      // Rs[colL][rowL]: colL = nf*32+l32 in [0,64), rowL in [0,128).
      const int vbase = (m0 >> 11) * 1024 + (n0 - 2048);
      const int srow0 = m0 & 2047;
#pragma unroll
      for (int g = 0; g < 4; ++g) {
        if (wc == g) {
#pragma unroll
          for (int nf = 0; nf < 2; ++nf) {
            const int colL = nf * 32 + l32;
#pragma unroll
            for (int mf = 0; mf < 2; ++mf)
#pragma unroll
              for (int rg = 0; rg < 4; ++rg) {
                u16x4 pk;
#pragma unroll
                for (int j = 0; j < 4; ++j) pk[j] = f2bf(acc[mf][nf][rg * 4 + j]);
                *(u16x4*)(Rs + colL * 264 + wr * 64 + mf * 32 + 8 * rg + 4 * lh) = pk;
              }
          }
        }
        __syncthreads();
        const int row_l = tid >> 3;
#pragma unroll
        for (int j = 0; j < 2; ++j) {
          const int c = (tid & 7) * 2 + j;
          u16x8 vv = *(const u16x8*)(Rs + row_l * 264 + c * 8);
          *(u16x8*)(vout + (size_t)(vbase + g * 64 + row_l) * S_ + srow0 + c * 8) = vv;
        }
        if (g < 3) __syncthreads();
      }
    }
    return;
  }
#undef ROWMAJOR_FLUSH
}

// ---------------- causal flash attention (unchanged from round 8) ----------
__global__ __launch_bounds__(256, 3) void k_attn(
    const unsigned short* __restrict__ qg, const unsigned short* __restrict__ kg,
    const unsigned short* __restrict__ vtg, unsigned short* __restrict__ ctx) {
  const int id = blockIdx.x;                 // 0..1023
  const int bh = (id & 7) + 8 * (id >> 7);   // head stays on one XCD (L2 locality)
  const int p  = (id >> 3) & 15;             // pair index
  const int qtA = p, qtB = 31 - p;           // (p+1)+(32-p)=33 tiles, all blocks equal
  const int tid = threadIdx.x, wid = tid >> 6, lane = tid & 63;
  const int l16 = lane & 15, lg = lane >> 4;
  __shared__ __align__(16) unsigned short Ks[2][64 * 64];      // 16 KB dbuf
  __shared__ __align__(16) unsigned short Vs[2][64 * 64];      // 16 KB dbuf
  __shared__ __align__(16) unsigned short Ps[4][2][16 * 72];   // 18 KB [wave][strip]

  const size_t headoff = (size_t)(bh >> 4) * ((size_t)S_ * D_) + (size_t)(bh & 15) * HD_;
  const unsigned short* Kb = kg + headoff;
  const unsigned short* Vt = vtg + (size_t)bh * ((size_t)HD_ * S_);

  const int qrowA = qtA * 64 + wid * 16 + l16;
  const int qrowB = qtB * 64 + wid * 16 + l16;
  s16x8 qfA0 = *(const s16x8*)(qg + headoff + (size_t)qrowA * D_ + lg * 8);
  s16x8 qfA1 = *(const s16x8*)(qg + headoff + (size_t)qrowA * D_ + 32 + lg * 8);
  s16x8 qfB0 = *(const s16x8*)(qg + headoff + (size_t)qrowB * D_ + lg * 8);
  s16x8 qfB1 = *(const s16x8*)(qg + headoff + (size_t)qrowB * D_ + 32 + lg * 8);

  f32x4 oA[4], oB[4];
#pragma unroll
  for (int n = 0; n < 4; ++n) { oA[n] = (f32x4)0.0f; oB[n] = (f32x4)0.0f; }
  float lsumA[4] = {0.f, 0.f, 0.f, 0.f};
  float lsumB[4] = {0.f, 0.f, 0.f, 0.f};
  unsigned short* psA = &Ps[wid][0][0];
  unsigned short* psB = &Ps[wid][1][0];
  const int myrowA = qtA * 64 + wid * 16 + lg * 4;
  const int myrowB = qtB * 64 + wid * 16 + lg * 4;
  const float L2E = 1.4426950408889634f;

  const unsigned short* kSrc[2];
  const unsigned short* vSrc[2];
  int dstOff[2];
#pragma unroll
  for (int i = 0; i < 2; ++i) {
    int chunk = (i * 4 + wid) * 64 + lane;
    int row = chunk >> 3, pc = chunk & 7;
    int scol = (pc ^ (row & 7)) * 8;
    kSrc[i] = Kb + (size_t)row * D_ + scol;
    vSrc[i] = Vt + (size_t)row * S_ + scol;
    dstOff[i] = (i * 4 + wid) * 1024;
  }

#pragma unroll
  for (int i = 0; i < 2; ++i) {
    GLD_LDS16(kSrc[i], (char*)Ks[0] + dstOff[i]);
    GLD_LDS16(vSrc[i], (char*)Vs[0] + dstOff[i]);
  }
  __syncthreads();

  for (int t = 0; t <= qtB; ++t) {
    const int cur = t & 1;
    const int kv0 = t * 64;
    const bool doA = (t <= qtA);
    if (t < qtB) {
      const int kvn = kv0 + 64;
#pragma unroll
      for (int i = 0; i < 2; ++i) {
        GLD_LDS16(kSrc[i] + (size_t)kvn * D_, (char*)Ks[cur ^ 1] + dstOff[i]);
        GLD_LDS16(vSrc[i] + kvn, (char*)Vs[cur ^ 1] + dstOff[i]);
      }
    }
    const unsigned short* Kc = Ks[cur];
    const unsigned short* Vc = Vs[cur];
    s16x8 kf0[4], kf1[4];
#pragma unroll
    for (int n = 0; n < 4; ++n) {
      int srow = n * 16 + l16, sw = srow & 7;
      kf0[n] = *(const s16x8*)(Kc + srow * 64 + (lg ^ sw) * 8);
      kf1[n] = *(const s16x8*)(Kc + srow * 64 + ((4 + lg) ^ sw) * 8);
    }
    f32x4 saA[4], saB[4];
    if (doA) {
#pragma unroll
      for (int n = 0; n < 4; ++n) {
        saA[n] = (f32x4)0.0f;
        saA[n] = __builtin_amdgcn_mfma_f32_16x16x32_bf16(qfA0, kf0[n], saA[n], 0, 0, 0);
        saA[n] = __builtin_amdgcn_mfma_f32_16x16x32_bf16(qfA1, kf1[n], saA[n], 0, 0, 0);
      }
    }
#pragma unroll
    for (int n = 0; n < 4; ++n) {
      saB[n] = (f32x4)0.0f;
      saB[n] = __builtin_amdgcn_mfma_f32_16x16x32_bf16(qfB0, kf0[n], saB[n], 0, 0, 0);
      saB[n] = __builtin_amdgcn_mfma_f32_16x16x32_bf16(qfB1, kf1[n], saB[n], 0, 0, 0);
    }
    if (doA) {
      const bool mask = (t == qtA);
#pragma unroll
      for (int r = 0; r < 4; ++r)
#pragma unroll
        for (int n = 0; n < 4; ++n) {
          float pv = exp2f((saA[n][r] - 12.0f) * L2E);
          if (mask && (kv0 + n * 16 + l16) > (myrowA + r)) pv = 0.0f;
          lsumA[r] += pv;
          psA[(lg * 4 + r) * 72 + n * 16 + l16] = f2bf(pv);
        }
    }
    {
      const bool mask = (t == qtB);
#pragma unroll
      for (int r = 0; r < 4; ++r)
#pragma unroll
        for (int n = 0; n < 4; ++n) {
          float pv = exp2f((saB[n][r] - 12.0f) * L2E);
          if (mask && (kv0 + n * 16 + l16) > (myrowB + r)) pv = 0.0f;
          lsumB[r] += pv;
          psB[(lg * 4 + r) * 72 + n * 16 + l16] = f2bf(pv);
        }
    }
    s16x8 vf0[4], vf1[4];
#pragma unroll
    for (int n = 0; n < 4; ++n) {
      int srow = n * 16 + l16, sw = srow & 7;
      vf0[n] = *(const s16x8*)(Vc + srow * 64 + (lg ^ sw) * 8);
      vf1[n] = *(const s16x8*)(Vc + srow * 64 + ((4 + lg) ^ sw) * 8);
    }
    __builtin_amdgcn_sched_barrier(0);
    asm volatile("s_waitcnt lgkmcnt(0)" ::: "memory");
    __builtin_amdgcn_sched_barrier(0);
    {
      s16x8 paB0 = *(const s16x8*)(psB + l16 * 72 + lg * 8);
      s16x8 paB1 = *(const s16x8*)(psB + l16 * 72 + 32 + lg * 8);
#pragma unroll
      for (int n = 0; n < 4; ++n) {
        oB[n] = __builtin_amdgcn_mfma_f32_16x16x32_bf16(paB0, vf0[n], oB[n], 0, 0, 0);
        oB[n] = __builtin_amdgcn_mfma_f32_16x16x32_bf16(paB1, vf1[n], oB[n], 0, 0, 0);
      }
      if (doA) {
        s16x8 paA0 = *(const s16x8*)(psA + l16 * 72 + lg * 8);
        s16x8 paA1 = *(const s16x8*)(psA + l16 * 72 + 32 + lg * 8);
#pragma unroll
        for (int n = 0; n < 4; ++n) {
          oA[n] = __builtin_amdgcn_mfma_f32_16x16x32_bf16(paA0, vf0[n], oA[n], 0, 0, 0);
          oA[n] = __builtin_amdgcn_mfma_f32_16x16x32_bf16(paA1, vf1[n], oA[n], 0, 0, 0);
        }
      }
    }
    __syncthreads();
  }

#pragma unroll
  for (int r = 0; r < 4; ++r) {
    float la = lsumA[r], lb = lsumB[r];
    la += __shfl_xor(la, 1); lb += __shfl_xor(lb, 1);
    la += __shfl_xor(la, 2); lb += __shfl_xor(lb, 2);
    la += __shfl_xor(la, 4); lb += __shfl_xor(lb, 4);
    la += __shfl_xor(la, 8); lb += __shfl_xor(lb, 8);
    float ia = 1.0f / la, ib = 1.0f / lb;
#pragma unroll
    for (int n = 0; n < 4; ++n) {
      ctx[headoff + (size_t)(myrowA + r) * D_ + n * 16 + l16] = f2bf(oA[n][r] * ia);
      ctx[headoff + (size_t)(myrowB + r) * D_ + n * 16 + l16] = f2bf(oB[n][r] * ib);
    }
  }
}

// ---------------- launch ----------------
extern "C" void kernel_launch(void* const* d_in, const int* in_sizes, int n_in,
                              void* d_out, int out_size, void* d_ws, size_t ws_size,
                              hipStream_t stream) {
  (void)in_sizes; (void)n_in; (void)out_size; (void)ws_size;
  const float* x   = (const float*)d_in[0];
  const float* Wq  = (const float*)d_in[1];
  const float* Wk  = (const float*)d_in[2];
  const float* Wv  = (const float*)d_in[3];
  const float* Wo  = (const float*)d_in[4];
  const float* bo  = (const float*)d_in[5];
  const float* W1  = (const float*)d_in[6];
  const float* b1  = (const float*)d_in[7];
  const float* W2  = (const float*)d_in[8];
  const float* b2  = (const float*)d_in[9];
  const float* g1  = (const float*)d_in[10];
  const float* be1 = (const float*)d_in[11];
  const float* g2  = (const float*)d_in[12];
  const float* be2 = (const float*)d_in[13];
  float* out = (float*)d_out;

  // workspace layout (136 MB): see earlier rounds
  char* w = (char*)d_ws;
  const size_t MB = 1ull << 20;
  unsigned short* wqkvT = (unsigned short*)(w + 0 * MB);
  unsigned short* woT   = (unsigned short*)(w + 6 * MB);
  unsigned short* w1T   = (unsigned short*)(w + 8 * MB);
  unsigned short* w2T   = (unsigned short*)(w + 16 * MB);
  unsigned short* hb    = (unsigned short*)(w + 24 * MB);
  float*          x2    = (float*)(w + 40 * MB);
  unsigned short* qkv   = (unsigned short*)(w + 72 * MB);   // qb | kb | vbT
  unsigned short* qb    = qkv;
  unsigned short* kb    = qkv + (size_t)MTOK * D_;
  unsigned short* vbT   = qkv + 2 * (size_t)MTOK * D_;
  unsigned short* cxb   = (unsigned short*)(w + 120 * MB);
  unsigned short* act   = (unsigned short*)(w + 72 * MB);   // aliases qkv region

  dim3 tb(32, 8);
  k_transpose<<<dim3(32, 32), tb, 0, stream>>>(Wq, wqkvT, 1024, 1024);
  k_transpose<<<dim3(32, 32), tb, 0, stream>>>(Wk, wqkvT + 1024 * 1024, 1024, 1024);
  k_transpose<<<dim3(32, 32), tb, 0, stream>>>(Wv, wqkvT + 2048 * 1024, 1024, 1024);
  k_transpose<<<dim3(32, 32), tb, 0, stream>>>(Wo, woT, 1024, 1024);
  k_transpose<<<dim3(128, 32), tb, 0, stream>>>(W1, w1T, 1024, 4096);
  k_transpose<<<dim3(32, 128), tb, 0, stream>>>(W2, w2T, 4096, 1024);

  k_layernorm<<<MTOK, 256, 0, stream>>>(x, g1, be1, hb);

  // QKV: (12, 64) = 768 blocks; groups 4n x 8m (2+2 MB L2-resident)
  k_gemmdp<3, 4, 8><<<dim3(12, 64), 512, 0, stream>>>(hb, wqkvT, nullptr, nullptr, qkv, nullptr, MTOK, 3072, 1024);

  k_attn<<<1024, 256, 0, stream>>>(qb, kb, vbT, cxb);

  // Wo: (4, 64) = 256 blocks; groups 4n x 8m
  k_gemmdp<2, 4, 8><<<dim3(4, 64), 512, 0, stream>>>(cxb, woT, bo, x, nullptr, x2, MTOK, 1024, 1024);

  k_layernorm<<<MTOK, 256, 0, stream>>>(x2, g2, be2, hb);

  // MLP1: (16, 64) = 1024 blocks; groups 4n x 8m
  k_gemmdp<1, 4, 8><<<dim3(16, 64), 512, 0, stream>>>(hb, w1T, b1, nullptr, act, nullptr, MTOK, 4096, 1024);
  // MLP2: (4, 64) = 256 blocks; groups 1n x 32m (B resident, A streams once)
  k_gemmdp<2, 1, 32><<<dim3(4, 64), 512, 0, stream>>>(act, w2T, b2, x2, nullptr, out, MTOK, 1024, 4096);
}

// Round 18
// 422.259 us; speedup vs baseline: 1.0852x; 1.0852x over previous
//
#include <hip/hip_runtime.h>
#include <cstdint>

// Problem constants
#define B_   4
#define S_   2048
#define D_   1024
#define H_   16
#define HD_  64
#define FF_  4096
#define MTOK 8192   // B_*S_

// may_alias: these type-pun LDS/global u16 buffers; without it TBAA treats
// short8-loads vs ushort-stores as no-alias and reorders them (round-2 NaN).
typedef short s16x8 __attribute__((ext_vector_type(8), may_alias));
typedef float f32x4 __attribute__((ext_vector_type(4)));
typedef unsigned short u16x4 __attribute__((ext_vector_type(4), may_alias));
typedef unsigned short u16x8 __attribute__((ext_vector_type(8), may_alias));

// async global->LDS, 16B per lane, dest = uniform base + lane*16
#define GLD_LDS16(g, l)                                                  \
  __builtin_amdgcn_global_load_lds(                                      \
      (__attribute__((address_space(1))) void*)(g),                      \
      (__attribute__((address_space(3))) void*)(l), 16, 0, 0)

__device__ __forceinline__ unsigned short f2bf(float f) {
  unsigned u = __float_as_uint(f);
  unsigned r = 0x7fffu + ((u >> 16) & 1u);   // RNE
  return (unsigned short)((u + r) >> 16);
}

// ---------------- weight transpose + fp32->bf16 ----------------
__global__ __launch_bounds__(256) void k_transpose(const float* __restrict__ in,
                                                   unsigned short* __restrict__ out,
                                                   int R, int C) {
  __shared__ float tile[32][33];
  int tx = threadIdx.x, ty = threadIdx.y;             // 32 x 8
  int c0 = blockIdx.x * 32, r0 = blockIdx.y * 32;
#pragma unroll
  for (int j = 0; j < 4; ++j)
    tile[ty + j * 8][tx] = in[(size_t)(r0 + ty + j * 8) * C + (c0 + tx)];
  __syncthreads();
#pragma unroll
  for (int j = 0; j < 4; ++j)
    out[(size_t)(c0 + ty + j * 8) * R + (r0 + tx)] = f2bf(tile[tx][ty + j * 8]);
}

// ---------------- LayerNorm (D=1024, one block per row) ----------------
__global__ __launch_bounds__(256) void k_layernorm(const float* __restrict__ x,
                                                   const float* __restrict__ g,
                                                   const float* __restrict__ be,
                                                   unsigned short* __restrict__ out) {
  int row = blockIdx.x, t = threadIdx.x;
  const float4* xr = (const float4*)(x + (size_t)row * D_);
  float4 v = xr[t];
  float s = v.x + v.y + v.z + v.w;
  float q = v.x * v.x + v.y * v.y + v.z * v.z + v.w * v.w;
#pragma unroll
  for (int o = 1; o < 64; o <<= 1) { s += __shfl_xor(s, o); q += __shfl_xor(q, o); }
  __shared__ float red[8];
  int wid = t >> 6;
  if ((t & 63) == 0) { red[wid * 2] = s; red[wid * 2 + 1] = q; }
  __syncthreads();
  s = red[0] + red[2] + red[4] + red[6];
  q = red[1] + red[3] + red[5] + red[7];
  float mean = s * (1.0f / D_);
  float rstd = rsqrtf(q * (1.0f / D_) - mean * mean + 1e-5f);
  float4 gv = ((const float4*)g)[t];
  float4 bv = ((const float4*)be)[t];
  u16x4 o4;
  o4[0] = f2bf(gv.x * (v.x - mean) * rstd + bv.x);
  o4[1] = f2bf(gv.y * (v.y - mean) * rstd + bv.y);
  o4[2] = f2bf(gv.z * (v.z - mean) * rstd + bv.z);
  o4[3] = f2bf(gv.w * (v.w - mean) * rstd + bv.w);
  *(u16x4*)(out + (size_t)row * D_ + t * 4) = o4;
}

// ---------------- 8-phase 256x256 GEMM (r13: m201 waits + reg-carry) -------
// Used for QKV (384 blocks). Iter = 2 K-tiles (8 phases); slots 0-3 even tile
// {A-lo,B-lo,B-hi,A-hi}, 4-7 odd. Stage at phase p targets the slot read at
// phase p-1; waits only at p3/p7 exit, vmcnt(6). Reg-carry quadrants.
template <int MODE>
__global__ __launch_bounds__(512, 2) void k_gemm8p(
    const unsigned short* __restrict__ A, const unsigned short* __restrict__ Bt,
    const float* __restrict__ bias,
    unsigned short* __restrict__ outb,
    int M, int N, int K) {
  __shared__ __align__(16) unsigned short smem[8 * 8192];   // 128KB
  unsigned short* const Rs = smem;                          // epilogue overlay

  const int tid = threadIdx.x;
  const int wid = tid >> 6, lane = tid & 63;
  const int l16 = lane & 15, lg = lane >> 4;
  const int wr = wid >> 2, wc = wid & 3;     // 2M x 4N waves
  const int nwg = gridDim.x * gridDim.y;
  const int id = blockIdx.y * gridDim.x + blockIdx.x;
  const int swz = (id & 7) * (nwg >> 3) + (id >> 3);
  const int m0 = (swz / gridDim.x) * 256, n0 = (swz % gridDim.x) * 256;

  f32x4 acc[8][4];
#pragma unroll
  for (int m = 0; m < 8; ++m)
#pragma unroll
    for (int n = 0; n < 4; ++n) acc[m][n] = (f32x4)0.0f;

  const int sRow = tid >> 3;
  const int sC = (((tid & 7) ^ (sRow & 7)) << 3);
  const unsigned short* aS0 = A + (size_t)(m0 + sRow) * K + sC;
  const unsigned short* aS1 = A + (size_t)(m0 + 64 + sRow) * K + sC;
  const unsigned short* aS2 = A + (size_t)(m0 + 128 + sRow) * K + sC;
  const unsigned short* aS3 = A + (size_t)(m0 + 192 + sRow) * K + sC;
  const unsigned short* bS0 = Bt + (size_t)(n0 + sRow) * K + sC;
  const unsigned short* bS1 = Bt + (size_t)(n0 + 64 + sRow) * K + sC;
  const unsigned short* bS2 = Bt + (size_t)(n0 + 128 + sRow) * K + sC;
  const unsigned short* bS3 = Bt + (size_t)(n0 + 192 + sRow) * K + sC;
  const int d0 = tid * 16, d1 = tid * 16 + 8192;

  const int cS0 = ((lg ^ (l16 & 7)) << 3);
  const int cS1 = (((4 + lg) ^ (l16 & 7)) << 3);

#define READ_A(SLOT)                                                           \
  _Pragma("unroll")                                                            \
  for (int m4 = 0; m4 < 4; ++m4) {                                             \
    const unsigned short* pr_ = smem + (SLOT) * 8192 + (wr * 64 + m4 * 16 + l16) * 64; \
    af[m4][0] = *(const s16x8*)(pr_ + cS0);                                    \
    af[m4][1] = *(const s16x8*)(pr_ + cS1);                                    \
  }
#define READ_B(SLOT, DEST)                                                     \
  _Pragma("unroll")                                                            \
  for (int n2 = 0; n2 < 2; ++n2) {                                             \
    const unsigned short* pr_ = smem + (SLOT) * 8192 + (wc * 32 + n2 * 16 + l16) * 64; \
    DEST[n2][0] = *(const s16x8*)(pr_ + cS0);                                  \
    DEST[n2][1] = *(const s16x8*)(pr_ + cS1);                                  \
  }
#define STAGE2(SLOT, P0_, P1_, KOFF)                                           \
  {                                                                            \
    char* dst_ = (char*)(smem + (SLOT) * 8192);                                \
    GLD_LDS16((P0_) + (KOFF), dst_ + d0);                                      \
    GLD_LDS16((P1_) + (KOFF), dst_ + d1);                                      \
  }
#define MFMAQ(MQ, NH, AF, BF)                                                  \
  __builtin_amdgcn_s_setprio(1);                                               \
  _Pragma("unroll")                                                            \
  for (int m4 = 0; m4 < 4; ++m4)                                               \
    _Pragma("unroll")                                                          \
    for (int n2 = 0; n2 < 2; ++n2) {                                           \
      acc[(MQ) * 4 + m4][(NH) * 2 + n2] = __builtin_amdgcn_mfma_f32_16x16x32_bf16( \
          AF[m4][0], BF[n2][0], acc[(MQ) * 4 + m4][(NH) * 2 + n2], 0, 0, 0);   \
      acc[(MQ) * 4 + m4][(NH) * 2 + n2] = __builtin_amdgcn_mfma_f32_16x16x32_bf16( \
          AF[m4][1], BF[n2][1], acc[(MQ) * 4 + m4][(NH) * 2 + n2], 0, 0, 0);   \
    }                                                                          \
  __builtin_amdgcn_s_setprio(0);
#define LGK0                                                                   \
  asm volatile("s_waitcnt lgkmcnt(0)" ::: "memory");                           \
  __builtin_amdgcn_sched_barrier(0);
#define BAR_ONLY                                                               \
  __builtin_amdgcn_sched_barrier(0);                                           \
  __builtin_amdgcn_s_barrier();

  STAGE2(0, aS0, aS1, 0)
  STAGE2(1, bS0, bS1, 0)
  STAGE2(2, bS2, bS3, 0)
  STAGE2(3, aS2, aS3, 0)
  STAGE2(4, aS0, aS1, 64)
  STAGE2(5, bS0, bS1, 64)
  STAGE2(6, bS2, bS3, 64)
  asm volatile("s_waitcnt vmcnt(0)" ::: "memory");
  BAR_ONLY

  const int nt2 = K / 128;
  for (int j = 0; j < nt2; ++j) {
    const bool stg = (j < nt2 - 1);
    const size_t k1 = (size_t)(2 * j + 1) * 64;
    const size_t k2 = (size_t)(2 * j + 2) * 64;
    const size_t k3 = (size_t)(2 * j + 3) * 64;
    s16x8 af[4][2], blo[2][2], bhi[2][2];
    READ_A(0)
    READ_B(1, blo)
    STAGE2(7, aS2, aS3, k1)
    LGK0
    MFMAQ(0, 0, af, blo)
    BAR_ONLY
    READ_B(2, bhi)
    if (stg) STAGE2(0, aS0, aS1, k2)
    LGK0
    MFMAQ(0, 1, af, bhi)
    BAR_ONLY
    READ_A(3)
    if (stg) STAGE2(1, bS0, bS1, k2)
    LGK0
    MFMAQ(1, 0, af, blo)
    BAR_ONLY
    if (stg) STAGE2(2, bS2, bS3, k2)
    MFMAQ(1, 1, af, bhi)
    if (stg) { asm volatile("s_waitcnt vmcnt(6)" ::: "memory"); }
    else     { asm volatile("s_waitcnt vmcnt(0)" ::: "memory"); }
    BAR_ONLY
    READ_A(4)
    READ_B(5, blo)
    if (stg) STAGE2(3, aS2, aS3, k2)
    LGK0
    MFMAQ(0, 0, af, blo)
    BAR_ONLY
    READ_B(6, bhi)
    if (stg) STAGE2(4, aS0, aS1, k3)
    LGK0
    MFMAQ(0, 1, af, bhi)
    BAR_ONLY
    READ_A(7)
    if (stg) STAGE2(5, bS0, bS1, k3)
    LGK0
    MFMAQ(1, 0, af, blo)
    BAR_ONLY
    if (stg) {
      STAGE2(6, bS2, bS3, k3)
      MFMAQ(1, 1, af, bhi)
      asm volatile("s_waitcnt vmcnt(6)" ::: "memory");
    } else {
      MFMAQ(1, 1, af, bhi)
    }
    BAR_ONLY
  }
#undef READ_A
#undef READ_B
#undef STAGE2
#undef MFMAQ
#undef LGK0
#undef BAR_ONLY

#define RM_FLUSH8(DSTPTR, NSTRIDE, COLBASE, XFORM)                             \
  {                                                                            \
    _Pragma("unroll")                                                          \
    for (int pr = 0; pr < 4; ++pr) {                                           \
      if (wr == (pr & 1)) {                                                    \
        const int mb_ = (pr >> 1) * 4;                                         \
        _Pragma("unroll")                                                      \
        for (int nn = 0; nn < 4; ++nn) {                                       \
          const int col = (nn >> 1) * 128 + wc * 32 + (nn & 1) * 16 + l16;     \
          _Pragma("unroll")                                                    \
          for (int m4 = 0; m4 < 4; ++m4) {                                     \
            _Pragma("unroll")                                                  \
            for (int r = 0; r < 4; ++r) {                                      \
              float xv = acc[mb_ + m4][nn][r];                                 \
              XFORM;                                                           \
              Rs[(m4 * 16 + lg * 4 + r) * 264 + col] = f2bf(xv);               \
            }                                                                  \
          }                                                                    \
        }                                                                      \
      }                                                                        \
      __syncthreads();                                                         \
      const int row_l = tid >> 3;                                              \
      _Pragma("unroll")                                                        \
      for (int j = 0; j < 4; ++j) {                                            \
        const int c = (tid & 7) * 4 + j;                                       \
        u16x8 vv = *(const u16x8*)(Rs + row_l * 264 + c * 8);                  \
        *(u16x8*)((DSTPTR) + (size_t)(m0 + pr * 64 + row_l) * (NSTRIDE) +      \
                  (COLBASE) + c * 8) = vv;                                     \
      }                                                                        \
      if (pr < 3) __syncthreads();                                             \
    }                                                                          \
  }

  if constexpr (MODE == 3) {
    unsigned short* qout = outb;
    unsigned short* kout = outb + (size_t)MTOK * D_;
    unsigned short* vout = outb + 2 * (size_t)MTOK * D_;
    if (n0 < 1024) {
      RM_FLUSH8(qout, D_, n0, { xv *= 0.125f; });
    } else if (n0 < 2048) {
      RM_FLUSH8(kout, D_, n0 - 1024, {});
    } else {
      const int vbase = (m0 >> 11) * 1024 + (n0 - 2048);
      const int srow0 = m0 & 2047;
#pragma unroll
      for (int cg = 0; cg < 4; ++cg) {
        if ((wc >> 1) == (cg & 1)) {
          const int nhh = (cg >> 1) * 2;
#pragma unroll
          for (int n2 = 0; n2 < 2; ++n2) {
            const int colL = (wc & 1) * 32 + n2 * 16 + l16;
#pragma unroll
            for (int m = 0; m < 8; ++m) {
              const int rowL = (m >> 2) * 128 + wr * 64 + (m & 3) * 16 + lg * 4;
              u16x4 pk;
#pragma unroll
              for (int r = 0; r < 4; ++r) pk[r] = f2bf(acc[m][nhh + n2][r]);
              *(u16x4*)(Rs + colL * 264 + rowL) = pk;
            }
          }
        }
        __syncthreads();
        const int colf = tid >> 3;
#pragma unroll
        for (int j = 0; j < 4; ++j) {
          u16x8 vv = *(const u16x8*)(Rs + colf * 264 + (tid & 7) * 32 + j * 8);
          *(u16x8*)(vout + (size_t)(vbase + cg * 64 + colf) * S_ + srow0 +
                    (tid & 7) * 32 + j * 8) = vv;
        }
        if (cg < 3) __syncthreads();
      }
    }
    return;
  }
#undef RM_FLUSH8
}

// ---------------- GEMM (r10 deep-pipeline, for Wo/MLP2) ----------
// BM=128 x BN=256 x BK=64, triple-buffered, counted vmcnt(6). MODE 2 only.
template <int MODE>
__global__ __launch_bounds__(512, 2) void k_gemmdp(
    const unsigned short* __restrict__ A, const unsigned short* __restrict__ Bt,
    const float* __restrict__ bias, const float* __restrict__ resid,
    unsigned short* __restrict__ outb, float* __restrict__ outf,
    int M, int N, int K) {
  constexpr int BM = 128, BN = 256, BK = 64;
  constexpr int AE = BM * BK;
  constexpr int BE = BN * BK;
  constexpr int BUF_E = AE + BE;
  __shared__ __align__(16) unsigned short smem[3 * BUF_E];   // 144KB

  const int tid = threadIdx.x;
  const int wid = tid >> 6, lane = tid & 63;
  const int l16 = lane & 15, lg = lane >> 4;
  const int wr = wid >> 2, wc = wid & 3;
  const int nwg = gridDim.x * gridDim.y;
  const int id = blockIdx.y * gridDim.x + blockIdx.x;
  const int swz = (id & 7) * (nwg >> 3) + (id >> 3);
  const int m0 = (swz / gridDim.x) * BM, n0 = (swz % gridDim.x) * BN;

  f32x4 acc[4][4];
#pragma unroll
  for (int m = 0; m < 4; ++m)
#pragma unroll
    for (int n = 0; n < 4; ++n) acc[m][n] = (f32x4)0.0f;

  const unsigned short* aSrc[2]; int aDstB[2];
  const unsigned short* bSrc[4]; int bDstB[4];
#pragma unroll
  for (int g = 0; g < 2; ++g) {
    int q = g * 512 + tid, row = q >> 3, c = q & 7;
    aSrc[g] = A + (size_t)(m0 + row) * K + ((c ^ (row & 7)) << 3);
    aDstB[g] = q * 16;
  }
#pragma unroll
  for (int g = 0; g < 4; ++g) {
    int q = g * 512 + tid, row = q >> 3, c = q & 7;
    bSrc[g] = Bt + (size_t)(n0 + row) * K + ((c ^ (row & 7)) << 3);
    bDstB[g] = q * 16;
  }
  int cSw[2];
  cSw[0] = ((lg) ^ (l16 & 7)) * 8;
  cSw[1] = ((4 + lg) ^ (l16 & 7)) * 8;
  const int aRow = (wr * 64 + l16) * BK;
  const int bRow = (wc * 64 + l16) * BK;

#define STAGE(ti)                                                              \
  {                                                                            \
    const int _b = (ti) % 3;                                                   \
    char* _pa = (char*)(smem + _b * BUF_E);                                    \
    char* _pb = (char*)(smem + _b * BUF_E + AE);                               \
    const int _kt = (ti) * BK;                                                 \
    _Pragma("unroll")                                                          \
    for (int g = 0; g < 2; ++g) GLD_LDS16(aSrc[g] + _kt, _pa + aDstB[g]);      \
    _Pragma("unroll")                                                          \
    for (int g = 0; g < 4; ++g) GLD_LDS16(bSrc[g] + _kt, _pb + bDstB[g]);      \
  }

  const int nt = K / BK;
  STAGE(0); STAGE(1);
  asm volatile("s_waitcnt vmcnt(6)" ::: "memory");
  __builtin_amdgcn_sched_barrier(0);
  __builtin_amdgcn_s_barrier();

  for (int i = 0; i < nt; ++i) {
    if (i + 2 < nt) STAGE(i + 2);
    const unsigned short* pa = smem + (i % 3) * BUF_E + aRow;
    const unsigned short* pb = smem + (i % 3) * BUF_E + AE + bRow;
    s16x8 af[4][2], bfr[4][2];
#pragma unroll
    for (int m = 0; m < 4; ++m) {
      af[m][0] = *(const s16x8*)(pa + m * 16 * BK + cSw[0]);
      af[m][1] = *(const s16x8*)(pa + m * 16 * BK + cSw[1]);
    }
#pragma unroll
    for (int n = 0; n < 4; ++n) {
      bfr[n][0] = *(const s16x8*)(pb + n * 16 * BK + cSw[0]);
      bfr[n][1] = *(const s16x8*)(pb + n * 16 * BK + cSw[1]);
    }
    asm volatile("s_waitcnt lgkmcnt(0)" ::: "memory");
    __builtin_amdgcn_sched_barrier(0);
    __builtin_amdgcn_s_setprio(1);
#pragma unroll
    for (int m = 0; m < 4; ++m)
#pragma unroll
      for (int n = 0; n < 4; ++n) {
        acc[m][n] = __builtin_amdgcn_mfma_f32_16x16x32_bf16(af[m][0], bfr[n][0], acc[m][n], 0, 0, 0);
        acc[m][n] = __builtin_amdgcn_mfma_f32_16x16x32_bf16(af[m][1], bfr[n][1], acc[m][n], 0, 0, 0);
      }
    __builtin_amdgcn_s_setprio(0);
    if (i < nt - 2) {
      asm volatile("s_waitcnt vmcnt(6)" ::: "memory");
    } else if (i == nt - 2) {
      asm volatile("s_waitcnt vmcnt(0)" ::: "memory");
    }
    __builtin_amdgcn_sched_barrier(0);
    __builtin_amdgcn_s_barrier();
  }
#undef STAGE

  if constexpr (MODE == 2) {
#pragma unroll
    for (int n = 0; n < 4; ++n) {
      const int col = n0 + wc * 64 + n * 16 + l16;
      const float bv = bias[col];
#pragma unroll
      for (int m = 0; m < 4; ++m)
#pragma unroll
        for (int r = 0; r < 4; ++r) {
          const int row = m0 + wr * 64 + m * 16 + lg * 4 + r;
          outf[(size_t)row * N + col] = acc[m][n][r] + bv + resid[(size_t)row * N + col];
        }
    }
  }
  (void)outb;
}

// ---------------- GEMM (r8 2-phase 128x128, 256 thr -- best MLP1) ----------
// MODE 1: +bias, GELU(exp2) -> bf16 via Rs repack (coalesced u16x8 stores).
template <int MODE>
__global__ __launch_bounds__(256) void k_gemm_bt(
    const unsigned short* __restrict__ A, const unsigned short* __restrict__ Bt,
    const float* __restrict__ bias,
    unsigned short* __restrict__ outb,
    int M, int N, int K) {
  // 32KB flat: As0 | As1 | Bs0 | Bs1 (4096 u16 each). Rs overlays [0..8704).
  __shared__ __align__(16) unsigned short smem[16384];
  unsigned short* const As0 = smem;
  unsigned short* const As1 = smem + 4096;
  unsigned short* const Bs0 = smem + 8192;
  unsigned short* const Bs1 = smem + 12288;
  unsigned short* const Rs  = smem;          // epilogue reuse
  const int tid = threadIdx.x;
  const int wid = tid >> 6, lane = tid & 63;
  const int nwg = gridDim.x * gridDim.y;
  const int id = blockIdx.y * gridDim.x + blockIdx.x;
  const int swz = (id & 7) * (nwg >> 3) + (id >> 3);
  const int m0 = (swz / gridDim.x) * 128, n0 = (swz % gridDim.x) * 128;
  const int wr = wid >> 1, wc = wid & 1;
  const int l16 = lane & 15, lg = lane >> 4;
  f32x4 acc[4][4];
#pragma unroll
  for (int m = 0; m < 4; ++m)
#pragma unroll
    for (int n = 0; n < 4; ++n) acc[m][n] = 0.0f;

  const unsigned short* aSrc[2];
  const unsigned short* bSrc[2];
  int dstOff[2];
#pragma unroll
  for (int i = 0; i < 2; ++i) {
    int chunk = (i * 4 + wid) * 64 + lane;   // 16B chunk id, 512 per 8KB tile
    int row = chunk >> 2, col = (chunk & 3) * 8;
    aSrc[i] = A + (size_t)(m0 + row) * K + col;
    bSrc[i] = Bt + (size_t)(n0 + row) * K + col;
    dstOff[i] = (i * 4 + wid) * 1024;        // bytes within an 8KB buffer
  }
  const int rdOffA = (wr * 64 + l16) * 32 + lg * 8;
  const int rdOffB = (wc * 64 + l16) * 32 + lg * 8;

  // prologue: stage kt=0 into buf 0
#pragma unroll
  for (int i = 0; i < 2; ++i) {
    GLD_LDS16(aSrc[i], (char*)As0 + dstOff[i]);
    GLD_LDS16(bSrc[i], (char*)Bs0 + dstOff[i]);
  }
  __syncthreads();

  int idx = 0;
  for (int kt = 0; kt < K; kt += 32, ++idx) {
    const int cur = idx & 1;
    if (kt + 32 < K) {
      char* aN = (char*)(cur ? As0 : As1);
      char* bN = (char*)(cur ? Bs0 : Bs1);
#pragma unroll
      for (int i = 0; i < 2; ++i) {
        GLD_LDS16(aSrc[i] + kt + 32, aN + dstOff[i]);
        GLD_LDS16(bSrc[i] + kt + 32, bN + dstOff[i]);
      }
    }
    const unsigned short* aRd = (cur ? As1 : As0) + rdOffA;
    const unsigned short* bRd = (cur ? Bs1 : Bs0) + rdOffB;
    s16x8 af[4], bfr[4];
#pragma unroll
    for (int m = 0; m < 4; ++m) af[m] = *(const s16x8*)(aRd + m * 16 * 32);
#pragma unroll
    for (int n = 0; n < 4; ++n) bfr[n] = *(const s16x8*)(bRd + n * 16 * 32);
#pragma unroll
    for (int m = 0; m < 4; ++m)
#pragma unroll
      for (int n = 0; n < 4; ++n)
        acc[m][n] = __builtin_amdgcn_mfma_f32_16x16x32_bf16(af[m], bfr[n], acc[m][n], 0, 0, 0);
    __syncthreads();
  }

  if constexpr (MODE == 1) {
#pragma unroll
    for (int p = 0; p < 2; ++p) {
      if (wr == p) {
#pragma unroll
        for (int n = 0; n < 4; ++n) {
#pragma unroll
          for (int mm = 0; mm < 4; ++mm) {
#pragma unroll
            for (int r = 0; r < 4; ++r) {
              float xv = acc[mm][n][r];
              xv += bias[n0 + wc * 64 + n * 16 + l16];
              float uu = 0.7978845608028654f * (xv + 0.044715f * xv * xv * xv);
              xv = xv * __builtin_amdgcn_rcpf(1.0f + __builtin_amdgcn_exp2f(uu * -2.885390081777927f));
              Rs[(mm * 16 + lg * 4 + r) * 136 + wc * 64 + n * 16 + l16] = f2bf(xv);
            }
          }
        }
      }
      __syncthreads();
      const int row_l = tid >> 2, seg = tid & 3;
#pragma unroll
      for (int j = 0; j < 4; ++j) {
        u16x8 vv = *(const u16x8*)(Rs + row_l * 136 + seg * 32 + j * 8);
        *(u16x8*)(outb + (size_t)(m0 + p * 64 + row_l) * N + n0 + seg * 32 + j * 8) = vv;
      }
      if (p == 0) __syncthreads();
    }
  }
}

// ---------------- causal flash attention (unchanged from round 8) ----------
__global__ __launch_bounds__(256, 3) void k_attn(
    const unsigned short* __restrict__ qg, const unsigned short* __restrict__ kg,
    const unsigned short* __restrict__ vtg, unsigned short* __restrict__ ctx) {
  const int id = blockIdx.x;                 // 0..1023
  const int bh = (id & 7) + 8 * (id >> 7);   // head stays on one XCD (L2 locality)
  const int p  = (id >> 3) & 15;             // pair index
  const int qtA = p, qtB = 31 - p;           // (p+1)+(32-p)=33 tiles, all blocks equal
  const int tid = threadIdx.x, wid = tid >> 6, lane = tid & 63;
  const int l16 = lane & 15, lg = lane >> 4;
  __shared__ __align__(16) unsigned short Ks[2][64 * 64];      // 16 KB dbuf
  __shared__ __align__(16) unsigned short Vs[2][64 * 64];      // 16 KB dbuf
  __shared__ __align__(16) unsigned short Ps[4][2][16 * 72];   // 18 KB [wave][strip]

  const size_t headoff = (size_t)(bh >> 4) * ((size_t)S_ * D_) + (size_t)(bh & 15) * HD_;
  const unsigned short* Kb = kg + headoff;
  const unsigned short* Vt = vtg + (size_t)bh * ((size_t)HD_ * S_);

  const int qrowA = qtA * 64 + wid * 16 + l16;
  const int qrowB = qtB * 64 + wid * 16 + l16;
  s16x8 qfA0 = *(const s16x8*)(qg + headoff + (size_t)qrowA * D_ + lg * 8);
  s16x8 qfA1 = *(const s16x8*)(qg + headoff + (size_t)qrowA * D_ + 32 + lg * 8);
  s16x8 qfB0 = *(const s16x8*)(qg + headoff + (size_t)qrowB * D_ + lg * 8);
  s16x8 qfB1 = *(const s16x8*)(qg + headoff + (size_t)qrowB * D_ + 32 + lg * 8);

  f32x4 oA[4], oB[4];
#pragma unroll
  for (int n = 0; n < 4; ++n) { oA[n] = (f32x4)0.0f; oB[n] = (f32x4)0.0f; }
  float lsumA[4] = {0.f, 0.f, 0.f, 0.f};
  float lsumB[4] = {0.f, 0.f, 0.f, 0.f};
  unsigned short* psA = &Ps[wid][0][0];
  unsigned short* psB = &Ps[wid][1][0];
  const int myrowA = qtA * 64 + wid * 16 + lg * 4;
  const int myrowB = qtB * 64 + wid * 16 + lg * 4;
  const float L2E = 1.4426950408889634f;

  const unsigned short* kSrc[2];
  const unsigned short* vSrc[2];
  int dstOff[2];
#pragma unroll
  for (int i = 0; i < 2; ++i) {
    int chunk = (i * 4 + wid) * 64 + lane;
    int row = chunk >> 3, pc = chunk & 7;
    int scol = (pc ^ (row & 7)) * 8;
    kSrc[i] = Kb + (size_t)row * D_ + scol;
    vSrc[i] = Vt + (size_t)row * S_ + scol;
    dstOff[i] = (i * 4 + wid) * 1024;
  }

#pragma unroll
  for (int i = 0; i < 2; ++i) {
    GLD_LDS16(kSrc[i], (char*)Ks[0] + dstOff[i]);
    GLD_LDS16(vSrc[i], (char*)Vs[0] + dstOff[i]);
  }
  __syncthreads();

  for (int t = 0; t <= qtB; ++t) {
    const int cur = t & 1;
    const int kv0 = t * 64;
    const bool doA = (t <= qtA);
    if (t < qtB) {
      const int kvn = kv0 + 64;
#pragma unroll
      for (int i = 0; i < 2; ++i) {
        GLD_LDS16(kSrc[i] + (size_t)kvn * D_, (char*)Ks[cur ^ 1] + dstOff[i]);
        GLD_LDS16(vSrc[i] + kvn, (char*)Vs[cur ^ 1] + dstOff[i]);
      }
    }
    const unsigned short* Kc = Ks[cur];
    const unsigned short* Vc = Vs[cur];
    s16x8 kf0[4], kf1[4];
#pragma unroll
    for (int n = 0; n < 4; ++n) {
      int srow = n * 16 + l16, sw = srow & 7;
      kf0[n] = *(const s16x8*)(Kc + srow * 64 + (lg ^ sw) * 8);
      kf1[n] = *(const s16x8*)(Kc + srow * 64 + ((4 + lg) ^ sw) * 8);
    }
    f32x4 saA[4], saB[4];
    if (doA) {
#pragma unroll
      for (int n = 0; n < 4; ++n) {
        saA[n] = (f32x4)0.0f;
        saA[n] = __builtin_amdgcn_mfma_f32_16x16x32_bf16(qfA0, kf0[n], saA[n], 0, 0, 0);
        saA[n] = __builtin_amdgcn_mfma_f32_16x16x32_bf16(qfA1, kf1[n], saA[n], 0, 0, 0);
      }
    }
#pragma unroll
    for (int n = 0; n < 4; ++n) {
      saB[n] = (f32x4)0.0f;
      saB[n] = __builtin_amdgcn_mfma_f32_16x16x32_bf16(qfB0, kf0[n], saB[n], 0, 0, 0);
      saB[n] = __builtin_amdgcn_mfma_f32_16x16x32_bf16(qfB1, kf1[n], saB[n], 0, 0, 0);
    }
    if (doA) {
      const bool mask = (t == qtA);
#pragma unroll
      for (int r = 0; r < 4; ++r)
#pragma unroll
        for (int n = 0; n < 4; ++n) {
          float pv = exp2f((saA[n][r] - 12.0f) * L2E);
          if (mask && (kv0 + n * 16 + l16) > (myrowA + r)) pv = 0.0f;
          lsumA[r] += pv;
          psA[(lg * 4 + r) * 72 + n * 16 + l16] = f2bf(pv);
        }
    }
    {
      const bool mask = (t == qtB);
#pragma unroll
      for (int r = 0; r < 4; ++r)
#pragma unroll
        for (int n = 0; n < 4; ++n) {
          float pv = exp2f((saB[n][r] - 12.0f) * L2E);
          if (mask && (kv0 + n * 16 + l16) > (myrowB + r)) pv = 0.0f;
          lsumB[r] += pv;
          psB[(lg * 4 + r) * 72 + n * 16 + l16] = f2bf(pv);
        }
    }
    s16x8 vf0[4], vf1[4];
#pragma unroll
    for (int n = 0; n < 4; ++n) {
      int srow = n * 16 + l16, sw = srow & 7;
      vf0[n] = *(const s16x8*)(Vc + srow * 64 + (lg ^ sw) * 8);
      vf1[n] = *(const s16x8*)(Vc + srow * 64 + ((4 + lg) ^ sw) * 8);
    }
    __builtin_amdgcn_sched_barrier(0);
    asm volatile("s_waitcnt lgkmcnt(0)" ::: "memory");
    __builtin_amdgcn_sched_barrier(0);
    {
      s16x8 paB0 = *(const s16x8*)(psB + l16 * 72 + lg * 8);
      s16x8 paB1 = *(const s16x8*)(psB + l16 * 72 + 32 + lg * 8);
#pragma unroll
      for (int n = 0; n < 4; ++n) {
        oB[n] = __builtin_amdgcn_mfma_f32_16x16x32_bf16(paB0, vf0[n], oB[n], 0, 0, 0);
        oB[n] = __builtin_amdgcn_mfma_f32_16x16x32_bf16(paB1, vf1[n], oB[n], 0, 0, 0);
      }
      if (doA) {
        s16x8 paA0 = *(const s16x8*)(psA + l16 * 72 + lg * 8);
        s16x8 paA1 = *(const s16x8*)(psA + l16 * 72 + 32 + lg * 8);
#pragma unroll
        for (int n = 0; n < 4; ++n) {
          oA[n] = __builtin_amdgcn_mfma_f32_16x16x32_bf16(paA0, vf0[n], oA[n], 0, 0, 0);
          oA[n] = __builtin_amdgcn_mfma_f32_16x16x32_bf16(paA1, vf1[n], oA[n], 0, 0, 0);
        }
      }
    }
    __syncthreads();
  }

#pragma unroll
  for (int r = 0; r < 4; ++r) {
    float la = lsumA[r], lb = lsumB[r];
    la += __shfl_xor(la, 1); lb += __shfl_xor(lb, 1);
    la += __shfl_xor(la, 2); lb += __shfl_xor(lb, 2);
    la += __shfl_xor(la, 4); lb += __shfl_xor(lb, 4);
    la += __shfl_xor(la, 8); lb += __shfl_xor(lb, 8);
    float ia = 1.0f / la, ib = 1.0f / lb;
#pragma unroll
    for (int n = 0; n < 4; ++n) {
      ctx[headoff + (size_t)(myrowA + r) * D_ + n * 16 + l16] = f2bf(oA[n][r] * ia);
      ctx[headoff + (size_t)(myrowB + r) * D_ + n * 16 + l16] = f2bf(oB[n][r] * ib);
    }
  }
}

// ---------------- launch ----------------
extern "C" void kernel_launch(void* const* d_in, const int* in_sizes, int n_in,
                              void* d_out, int out_size, void* d_ws, size_t ws_size,
                              hipStream_t stream) {
  (void)in_sizes; (void)n_in; (void)out_size; (void)ws_size;
  const float* x   = (const float*)d_in[0];
  const float* Wq  = (const float*)d_in[1];
  const float* Wk  = (const float*)d_in[2];
  const float* Wv  = (const float*)d_in[3];
  const float* Wo  = (const float*)d_in[4];
  const float* bo  = (const float*)d_in[5];
  const float* W1  = (const float*)d_in[6];
  const float* b1  = (const float*)d_in[7];
  const float* W2  = (const float*)d_in[8];
  const float* b2  = (const float*)d_in[9];
  const float* g1  = (const float*)d_in[10];
  const float* be1 = (const float*)d_in[11];
  const float* g2  = (const float*)d_in[12];
  const float* be2 = (const float*)d_in[13];
  float* out = (float*)d_out;

  // workspace layout (136 MB): see earlier rounds
  char* w = (char*)d_ws;
  const size_t MB = 1ull << 20;
  unsigned short* wqkvT = (unsigned short*)(w + 0 * MB);
  unsigned short* woT   = (unsigned short*)(w + 6 * MB);
  unsigned short* w1T   = (unsigned short*)(w + 8 * MB);
  unsigned short* w2T   = (unsigned short*)(w + 16 * MB);
  unsigned short* hb    = (unsigned short*)(w + 24 * MB);
  float*          x2    = (float*)(w + 40 * MB);
  unsigned short* qkv   = (unsigned short*)(w + 72 * MB);   // qb | kb | vbT
  unsigned short* qb    = qkv;
  unsigned short* kb    = qkv + (size_t)MTOK * D_;
  unsigned short* vbT   = qkv + 2 * (size_t)MTOK * D_;
  unsigned short* cxb   = (unsigned short*)(w + 120 * MB);
  unsigned short* act   = (unsigned short*)(w + 72 * MB);   // aliases qkv region

  dim3 tb(32, 8);
  k_transpose<<<dim3(32, 32), tb, 0, stream>>>(Wq, wqkvT, 1024, 1024);
  k_transpose<<<dim3(32, 32), tb, 0, stream>>>(Wk, wqkvT + 1024 * 1024, 1024, 1024);
  k_transpose<<<dim3(32, 32), tb, 0, stream>>>(Wv, wqkvT + 2048 * 1024, 1024, 1024);
  k_transpose<<<dim3(32, 32), tb, 0, stream>>>(Wo, woT, 1024, 1024);
  k_transpose<<<dim3(128, 32), tb, 0, stream>>>(W1, w1T, 1024, 4096);
  k_transpose<<<dim3(32, 128), tb, 0, stream>>>(W2, w2T, 4096, 1024);

  k_layernorm<<<MTOK, 256, 0, stream>>>(x, g1, be1, hb);

  // QKV: 8-phase 256^2 (r13 best) -> (12, 32) = 384 blocks
  k_gemm8p<3><<<dim3(12, 32), 512, 0, stream>>>(hb, wqkvT, nullptr, qkv, MTOK, 3072, 1024);

  k_attn<<<1024, 256, 0, stream>>>(qb, kb, vbT, cxb);

  // Wo: r10 gemmdp -> (4, 64) = 256 blocks
  k_gemmdp<2><<<dim3(4, 64), 512, 0, stream>>>(cxb, woT, bo, x, nullptr, x2, MTOK, 1024, 1024);

  k_layernorm<<<MTOK, 256, 0, stream>>>(x2, g2, be2, hb);

  // MLP1: r8 2-phase 128^2 (best MLP1 measurement) -> (32, 64) = 2048 blocks
  k_gemm_bt<1><<<dim3(32, 64), 256, 0, stream>>>(hb, w1T, b1, act, MTOK, 4096, 1024);
  // MLP2: r10 gemmdp -> (4, 64) = 256 blocks
  k_gemmdp<2><<<dim3(4, 64), 512, 0, stream>>>(act, w2T, b2, x2, nullptr, out, MTOK, 1024, 4096);
}

// Round 19
// 412.773 us; speedup vs baseline: 1.1101x; 1.0230x over previous
//
#include <hip/hip_runtime.h>
#include <cstdint>

// Problem constants
#define B_   4
#define S_   2048
#define D_   1024
#define H_   16
#define HD_  64
#define FF_  4096
#define MTOK 8192   // B_*S_

// may_alias: these type-pun LDS/global u16 buffers; without it TBAA treats
// short8-loads vs ushort-stores as no-alias and reorders them (round-2 NaN).
typedef short s16x8 __attribute__((ext_vector_type(8), may_alias));
typedef float f32x4 __attribute__((ext_vector_type(4)));
typedef unsigned short u16x4 __attribute__((ext_vector_type(4), may_alias));
typedef unsigned short u16x8 __attribute__((ext_vector_type(8), may_alias));

// async global->LDS, 16B per lane, dest = uniform base + lane*16
#define GLD_LDS16(g, l)                                                  \
  __builtin_amdgcn_global_load_lds(                                      \
      (__attribute__((address_space(1))) void*)(g),                      \
      (__attribute__((address_space(3))) void*)(l), 16, 0, 0)

__device__ __forceinline__ unsigned short f2bf(float f) {
  unsigned u = __float_as_uint(f);
  unsigned r = 0x7fffu + ((u >> 16) & 1u);   // RNE
  return (unsigned short)((u + r) >> 16);
}

// ---------------- weight transpose + fp32->bf16 ----------------
__global__ __launch_bounds__(256) void k_transpose(const float* __restrict__ in,
                                                   unsigned short* __restrict__ out,
                                                   int R, int C) {
  __shared__ float tile[32][33];
  int tx = threadIdx.x, ty = threadIdx.y;             // 32 x 8
  int c0 = blockIdx.x * 32, r0 = blockIdx.y * 32;
#pragma unroll
  for (int j = 0; j < 4; ++j)
    tile[ty + j * 8][tx] = in[(size_t)(r0 + ty + j * 8) * C + (c0 + tx)];
  __syncthreads();
#pragma unroll
  for (int j = 0; j < 4; ++j)
    out[(size_t)(c0 + ty + j * 8) * R + (r0 + tx)] = f2bf(tile[tx][ty + j * 8]);
}

// ---------------- LayerNorm (D=1024, one block per row) ----------------
__global__ __launch_bounds__(256) void k_layernorm(const float* __restrict__ x,
                                                   const float* __restrict__ g,
                                                   const float* __restrict__ be,
                                                   unsigned short* __restrict__ out) {
  int row = blockIdx.x, t = threadIdx.x;
  const float4* xr = (const float4*)(x + (size_t)row * D_);
  float4 v = xr[t];
  float s = v.x + v.y + v.z + v.w;
  float q = v.x * v.x + v.y * v.y + v.z * v.z + v.w * v.w;
#pragma unroll
  for (int o = 1; o < 64; o <<= 1) { s += __shfl_xor(s, o); q += __shfl_xor(q, o); }
  __shared__ float red[8];
  int wid = t >> 6;
  if ((t & 63) == 0) { red[wid * 2] = s; red[wid * 2 + 1] = q; }
  __syncthreads();
  s = red[0] + red[2] + red[4] + red[6];
  q = red[1] + red[3] + red[5] + red[7];
  float mean = s * (1.0f / D_);
  float rstd = rsqrtf(q * (1.0f / D_) - mean * mean + 1e-5f);
  float4 gv = ((const float4*)g)[t];
  float4 bv = ((const float4*)be)[t];
  u16x4 o4;
  o4[0] = f2bf(gv.x * (v.x - mean) * rstd + bv.x);
  o4[1] = f2bf(gv.y * (v.y - mean) * rstd + bv.y);
  o4[2] = f2bf(gv.z * (v.z - mean) * rstd + bv.z);
  o4[3] = f2bf(gv.w * (v.w - mean) * rstd + bv.w);
  *(u16x4*)(out + (size_t)row * D_ + t * 4) = o4;
}

// ---------------- 8-phase 256x256 GEMM (r13: m201 waits + reg-carry) -------
// QKV (384 blocks) + MLP1 (512 blocks). Iter = 2 K-tiles (8 phases); slots
// 0-3 even tile {A-lo,B-lo,B-hi,A-hi}, 4-7 odd. Stage at phase p targets the
// slot read at phase p-1; waits only at p3/p7 exit, vmcnt(6). Reg-carry
// quadrants: P0 reads 12, P1 reads 4, P2 reads 8, P3 reads 0.
template <int MODE>
__global__ __launch_bounds__(512, 2) void k_gemm8p(
    const unsigned short* __restrict__ A, const unsigned short* __restrict__ Bt,
    const float* __restrict__ bias,
    unsigned short* __restrict__ outb,
    int M, int N, int K) {
  __shared__ __align__(16) unsigned short smem[8 * 8192];   // 128KB
  unsigned short* const Rs = smem;                          // epilogue overlay

  const int tid = threadIdx.x;
  const int wid = tid >> 6, lane = tid & 63;
  const int l16 = lane & 15, lg = lane >> 4;
  const int wr = wid >> 2, wc = wid & 3;     // 2M x 4N waves
  const int nwg = gridDim.x * gridDim.y;
  const int id = blockIdx.y * gridDim.x + blockIdx.x;
  const int swz = (id & 7) * (nwg >> 3) + (id >> 3);
  const int m0 = (swz / gridDim.x) * 256, n0 = (swz % gridDim.x) * 256;

  f32x4 acc[8][4];
#pragma unroll
  for (int m = 0; m < 8; ++m)
#pragma unroll
    for (int n = 0; n < 4; ++n) acc[m][n] = (f32x4)0.0f;

  const int sRow = tid >> 3;
  const int sC = (((tid & 7) ^ (sRow & 7)) << 3);
  const unsigned short* aS0 = A + (size_t)(m0 + sRow) * K + sC;
  const unsigned short* aS1 = A + (size_t)(m0 + 64 + sRow) * K + sC;
  const unsigned short* aS2 = A + (size_t)(m0 + 128 + sRow) * K + sC;
  const unsigned short* aS3 = A + (size_t)(m0 + 192 + sRow) * K + sC;
  const unsigned short* bS0 = Bt + (size_t)(n0 + sRow) * K + sC;
  const unsigned short* bS1 = Bt + (size_t)(n0 + 64 + sRow) * K + sC;
  const unsigned short* bS2 = Bt + (size_t)(n0 + 128 + sRow) * K + sC;
  const unsigned short* bS3 = Bt + (size_t)(n0 + 192 + sRow) * K + sC;
  const int d0 = tid * 16, d1 = tid * 16 + 8192;

  const int cS0 = ((lg ^ (l16 & 7)) << 3);
  const int cS1 = (((4 + lg) ^ (l16 & 7)) << 3);

#define READ_A(SLOT)                                                           \
  _Pragma("unroll")                                                            \
  for (int m4 = 0; m4 < 4; ++m4) {                                             \
    const unsigned short* pr_ = smem + (SLOT) * 8192 + (wr * 64 + m4 * 16 + l16) * 64; \
    af[m4][0] = *(const s16x8*)(pr_ + cS0);                                    \
    af[m4][1] = *(const s16x8*)(pr_ + cS1);                                    \
  }
#define READ_B(SLOT, DEST)                                                     \
  _Pragma("unroll")                                                            \
  for (int n2 = 0; n2 < 2; ++n2) {                                             \
    const unsigned short* pr_ = smem + (SLOT) * 8192 + (wc * 32 + n2 * 16 + l16) * 64; \
    DEST[n2][0] = *(const s16x8*)(pr_ + cS0);                                  \
    DEST[n2][1] = *(const s16x8*)(pr_ + cS1);                                  \
  }
#define STAGE2(SLOT, P0_, P1_, KOFF)                                           \
  {                                                                            \
    char* dst_ = (char*)(smem + (SLOT) * 8192);                                \
    GLD_LDS16((P0_) + (KOFF), dst_ + d0);                                      \
    GLD_LDS16((P1_) + (KOFF), dst_ + d1);                                      \
  }
#define MFMAQ(MQ, NH, AF, BF)                                                  \
  __builtin_amdgcn_s_setprio(1);                                               \
  _Pragma("unroll")                                                            \
  for (int m4 = 0; m4 < 4; ++m4)                                               \
    _Pragma("unroll")                                                          \
    for (int n2 = 0; n2 < 2; ++n2) {                                           \
      acc[(MQ) * 4 + m4][(NH) * 2 + n2] = __builtin_amdgcn_mfma_f32_16x16x32_bf16( \
          AF[m4][0], BF[n2][0], acc[(MQ) * 4 + m4][(NH) * 2 + n2], 0, 0, 0);   \
      acc[(MQ) * 4 + m4][(NH) * 2 + n2] = __builtin_amdgcn_mfma_f32_16x16x32_bf16( \
          AF[m4][1], BF[n2][1], acc[(MQ) * 4 + m4][(NH) * 2 + n2], 0, 0, 0);   \
    }                                                                          \
  __builtin_amdgcn_s_setprio(0);
#define LGK0                                                                   \
  asm volatile("s_waitcnt lgkmcnt(0)" ::: "memory");                           \
  __builtin_amdgcn_sched_barrier(0);
#define BAR_ONLY                                                               \
  __builtin_amdgcn_sched_barrier(0);                                           \
  __builtin_amdgcn_s_barrier();

  STAGE2(0, aS0, aS1, 0)
  STAGE2(1, bS0, bS1, 0)
  STAGE2(2, bS2, bS3, 0)
  STAGE2(3, aS2, aS3, 0)
  STAGE2(4, aS0, aS1, 64)
  STAGE2(5, bS0, bS1, 64)
  STAGE2(6, bS2, bS3, 64)
  asm volatile("s_waitcnt vmcnt(0)" ::: "memory");
  BAR_ONLY

  const int nt2 = K / 128;
  for (int j = 0; j < nt2; ++j) {
    const bool stg = (j < nt2 - 1);
    const size_t k1 = (size_t)(2 * j + 1) * 64;
    const size_t k2 = (size_t)(2 * j + 2) * 64;
    const size_t k3 = (size_t)(2 * j + 3) * 64;
    s16x8 af[4][2], blo[2][2], bhi[2][2];
    READ_A(0)
    READ_B(1, blo)
    STAGE2(7, aS2, aS3, k1)
    LGK0
    MFMAQ(0, 0, af, blo)
    BAR_ONLY
    READ_B(2, bhi)
    if (stg) STAGE2(0, aS0, aS1, k2)
    LGK0
    MFMAQ(0, 1, af, bhi)
    BAR_ONLY
    READ_A(3)
    if (stg) STAGE2(1, bS0, bS1, k2)
    LGK0
    MFMAQ(1, 0, af, blo)
    BAR_ONLY
    if (stg) STAGE2(2, bS2, bS3, k2)
    MFMAQ(1, 1, af, bhi)
    if (stg) { asm volatile("s_waitcnt vmcnt(6)" ::: "memory"); }
    else     { asm volatile("s_waitcnt vmcnt(0)" ::: "memory"); }
    BAR_ONLY
    READ_A(4)
    READ_B(5, blo)
    if (stg) STAGE2(3, aS2, aS3, k2)
    LGK0
    MFMAQ(0, 0, af, blo)
    BAR_ONLY
    READ_B(6, bhi)
    if (stg) STAGE2(4, aS0, aS1, k3)
    LGK0
    MFMAQ(0, 1, af, bhi)
    BAR_ONLY
    READ_A(7)
    if (stg) STAGE2(5, bS0, bS1, k3)
    LGK0
    MFMAQ(1, 0, af, blo)
    BAR_ONLY
    if (stg) {
      STAGE2(6, bS2, bS3, k3)
      MFMAQ(1, 1, af, bhi)
      asm volatile("s_waitcnt vmcnt(6)" ::: "memory");
    } else {
      MFMAQ(1, 1, af, bhi)
    }
    BAR_ONLY
  }
#undef READ_A
#undef READ_B
#undef STAGE2
#undef MFMAQ
#undef LGK0
#undef BAR_ONLY

#define RM_FLUSH8(DSTPTR, NSTRIDE, COLBASE, XFORM)                             \
  {                                                                            \
    _Pragma("unroll")                                                          \
    for (int pr = 0; pr < 4; ++pr) {                                           \
      if (wr == (pr & 1)) {                                                    \
        const int mb_ = (pr >> 1) * 4;                                         \
        _Pragma("unroll")                                                      \
        for (int nn = 0; nn < 4; ++nn) {                                       \
          const int col = (nn >> 1) * 128 + wc * 32 + (nn & 1) * 16 + l16;     \
          _Pragma("unroll")                                                    \
          for (int m4 = 0; m4 < 4; ++m4) {                                     \
            _Pragma("unroll")                                                  \
            for (int r = 0; r < 4; ++r) {                                      \
              float xv = acc[mb_ + m4][nn][r];                                 \
              XFORM;                                                           \
              Rs[(m4 * 16 + lg * 4 + r) * 264 + col] = f2bf(xv);               \
            }                                                                  \
          }                                                                    \
        }                                                                      \
      }                                                                        \
      __syncthreads();                                                         \
      const int row_l = tid >> 3;                                              \
      _Pragma("unroll")                                                        \
      for (int j = 0; j < 4; ++j) {                                            \
        const int c = (tid & 7) * 4 + j;                                       \
        u16x8 vv = *(const u16x8*)(Rs + row_l * 264 + c * 8);                  \
        *(u16x8*)((DSTPTR) + (size_t)(m0 + pr * 64 + row_l) * (NSTRIDE) +      \
                  (COLBASE) + c * 8) = vv;                                     \
      }                                                                        \
      if (pr < 3) __syncthreads();                                             \
    }                                                                          \
  }

  if constexpr (MODE == 1) {
    RM_FLUSH8(outb, N, n0, {
      xv += bias[n0 + col];
      float uu = 0.7978845608028654f * (xv + 0.044715f * xv * xv * xv);
      xv = xv * __builtin_amdgcn_rcpf(1.0f + __builtin_amdgcn_exp2f(uu * -2.885390081777927f));
    });
    return;
  }

  if constexpr (MODE == 3) {
    unsigned short* qout = outb;
    unsigned short* kout = outb + (size_t)MTOK * D_;
    unsigned short* vout = outb + 2 * (size_t)MTOK * D_;
    if (n0 < 1024) {
      RM_FLUSH8(qout, D_, n0, { xv *= 0.125f; });
    } else if (n0 < 2048) {
      RM_FLUSH8(kout, D_, n0 - 1024, {});
    } else {
      const int vbase = (m0 >> 11) * 1024 + (n0 - 2048);
      const int srow0 = m0 & 2047;
#pragma unroll
      for (int cg = 0; cg < 4; ++cg) {
        if ((wc >> 1) == (cg & 1)) {
          const int nhh = (cg >> 1) * 2;
#pragma unroll
          for (int n2 = 0; n2 < 2; ++n2) {
            const int colL = (wc & 1) * 32 + n2 * 16 + l16;
#pragma unroll
            for (int m = 0; m < 8; ++m) {
              const int rowL = (m >> 2) * 128 + wr * 64 + (m & 3) * 16 + lg * 4;
              u16x4 pk;
#pragma unroll
              for (int r = 0; r < 4; ++r) pk[r] = f2bf(acc[m][nhh + n2][r]);
              *(u16x4*)(Rs + colL * 264 + rowL) = pk;
            }
          }
        }
        __syncthreads();
        const int colf = tid >> 3;
#pragma unroll
        for (int j = 0; j < 4; ++j) {
          u16x8 vv = *(const u16x8*)(Rs + colf * 264 + (tid & 7) * 32 + j * 8);
          *(u16x8*)(vout + (size_t)(vbase + cg * 64 + colf) * S_ + srow0 +
                    (tid & 7) * 32 + j * 8) = vv;
        }
        if (cg < 3) __syncthreads();
      }
    }
    return;
  }
#undef RM_FLUSH8
}

// ---------------- GEMM (r10 deep-pipeline, for Wo/MLP2) ----------
// BM=128 x BN=256 x BK=64, triple-buffered, counted vmcnt(6). MODE 2 only.
template <int MODE>
__global__ __launch_bounds__(512, 2) void k_gemmdp(
    const unsigned short* __restrict__ A, const unsigned short* __restrict__ Bt,
    const float* __restrict__ bias, const float* __restrict__ resid,
    unsigned short* __restrict__ outb, float* __restrict__ outf,
    int M, int N, int K) {
  constexpr int BM = 128, BN = 256, BK = 64;
  constexpr int AE = BM * BK;
  constexpr int BE = BN * BK;
  constexpr int BUF_E = AE + BE;
  __shared__ __align__(16) unsigned short smem[3 * BUF_E];   // 144KB

  const int tid = threadIdx.x;
  const int wid = tid >> 6, lane = tid & 63;
  const int l16 = lane & 15, lg = lane >> 4;
  const int wr = wid >> 2, wc = wid & 3;
  const int nwg = gridDim.x * gridDim.y;
  const int id = blockIdx.y * gridDim.x + blockIdx.x;
  const int swz = (id & 7) * (nwg >> 3) + (id >> 3);
  const int m0 = (swz / gridDim.x) * BM, n0 = (swz % gridDim.x) * BN;

  f32x4 acc[4][4];
#pragma unroll
  for (int m = 0; m < 4; ++m)
#pragma unroll
    for (int n = 0; n < 4; ++n) acc[m][n] = (f32x4)0.0f;

  const unsigned short* aSrc[2]; int aDstB[2];
  const unsigned short* bSrc[4]; int bDstB[4];
#pragma unroll
  for (int g = 0; g < 2; ++g) {
    int q = g * 512 + tid, row = q >> 3, c = q & 7;
    aSrc[g] = A + (size_t)(m0 + row) * K + ((c ^ (row & 7)) << 3);
    aDstB[g] = q * 16;
  }
#pragma unroll
  for (int g = 0; g < 4; ++g) {
    int q = g * 512 + tid, row = q >> 3, c = q & 7;
    bSrc[g] = Bt + (size_t)(n0 + row) * K + ((c ^ (row & 7)) << 3);
    bDstB[g] = q * 16;
  }
  int cSw[2];
  cSw[0] = ((lg) ^ (l16 & 7)) * 8;
  cSw[1] = ((4 + lg) ^ (l16 & 7)) * 8;
  const int aRow = (wr * 64 + l16) * BK;
  const int bRow = (wc * 64 + l16) * BK;

#define STAGE(ti)                                                              \
  {                                                                            \
    const int _b = (ti) % 3;                                                   \
    char* _pa = (char*)(smem + _b * BUF_E);                                    \
    char* _pb = (char*)(smem + _b * BUF_E + AE);                               \
    const int _kt = (ti) * BK;                                                 \
    _Pragma("unroll")                                                          \
    for (int g = 0; g < 2; ++g) GLD_LDS16(aSrc[g] + _kt, _pa + aDstB[g]);      \
    _Pragma("unroll")                                                          \
    for (int g = 0; g < 4; ++g) GLD_LDS16(bSrc[g] + _kt, _pb + bDstB[g]);      \
  }

  const int nt = K / BK;
  STAGE(0); STAGE(1);
  asm volatile("s_waitcnt vmcnt(6)" ::: "memory");
  __builtin_amdgcn_sched_barrier(0);
  __builtin_amdgcn_s_barrier();

  for (int i = 0; i < nt; ++i) {
    if (i + 2 < nt) STAGE(i + 2);
    const unsigned short* pa = smem + (i % 3) * BUF_E + aRow;
    const unsigned short* pb = smem + (i % 3) * BUF_E + AE + bRow;
    s16x8 af[4][2], bfr[4][2];
#pragma unroll
    for (int m = 0; m < 4; ++m) {
      af[m][0] = *(const s16x8*)(pa + m * 16 * BK + cSw[0]);
      af[m][1] = *(const s16x8*)(pa + m * 16 * BK + cSw[1]);
    }
#pragma unroll
    for (int n = 0; n < 4; ++n) {
      bfr[n][0] = *(const s16x8*)(pb + n * 16 * BK + cSw[0]);
      bfr[n][1] = *(const s16x8*)(pb + n * 16 * BK + cSw[1]);
    }
    asm volatile("s_waitcnt lgkmcnt(0)" ::: "memory");
    __builtin_amdgcn_sched_barrier(0);
    __builtin_amdgcn_s_setprio(1);
#pragma unroll
    for (int m = 0; m < 4; ++m)
#pragma unroll
      for (int n = 0; n < 4; ++n) {
        acc[m][n] = __builtin_amdgcn_mfma_f32_16x16x32_bf16(af[m][0], bfr[n][0], acc[m][n], 0, 0, 0);
        acc[m][n] = __builtin_amdgcn_mfma_f32_16x16x32_bf16(af[m][1], bfr[n][1], acc[m][n], 0, 0, 0);
      }
    __builtin_amdgcn_s_setprio(0);
    if (i < nt - 2) {
      asm volatile("s_waitcnt vmcnt(6)" ::: "memory");
    } else if (i == nt - 2) {
      asm volatile("s_waitcnt vmcnt(0)" ::: "memory");
    }
    __builtin_amdgcn_sched_barrier(0);
    __builtin_amdgcn_s_barrier();
  }
#undef STAGE

  if constexpr (MODE == 2) {
#pragma unroll
    for (int n = 0; n < 4; ++n) {
      const int col = n0 + wc * 64 + n * 16 + l16;
      const float bv = bias[col];
#pragma unroll
      for (int m = 0; m < 4; ++m)
#pragma unroll
        for (int r = 0; r < 4; ++r) {
          const int row = m0 + wr * 64 + m * 16 + lg * 4 + r;
          outf[(size_t)row * N + col] = acc[m][n][r] + bv + resid[(size_t)row * N + col];
        }
    }
  }
  (void)outb;
}

// ---------------- causal flash attention (unchanged from round 8) ----------
__global__ __launch_bounds__(256, 3) void k_attn(
    const unsigned short* __restrict__ qg, const unsigned short* __restrict__ kg,
    const unsigned short* __restrict__ vtg, unsigned short* __restrict__ ctx) {
  const int id = blockIdx.x;                 // 0..1023
  const int bh = (id & 7) + 8 * (id >> 7);   // head stays on one XCD (L2 locality)
  const int p  = (id >> 3) & 15;             // pair index
  const int qtA = p, qtB = 31 - p;           // (p+1)+(32-p)=33 tiles, all blocks equal
  const int tid = threadIdx.x, wid = tid >> 6, lane = tid & 63;
  const int l16 = lane & 15, lg = lane >> 4;
  __shared__ __align__(16) unsigned short Ks[2][64 * 64];      // 16 KB dbuf
  __shared__ __align__(16) unsigned short Vs[2][64 * 64];      // 16 KB dbuf
  __shared__ __align__(16) unsigned short Ps[4][2][16 * 72];   // 18 KB [wave][strip]

  const size_t headoff = (size_t)(bh >> 4) * ((size_t)S_ * D_) + (size_t)(bh & 15) * HD_;
  const unsigned short* Kb = kg + headoff;
  const unsigned short* Vt = vtg + (size_t)bh * ((size_t)HD_ * S_);

  const int qrowA = qtA * 64 + wid * 16 + l16;
  const int qrowB = qtB * 64 + wid * 16 + l16;
  s16x8 qfA0 = *(const s16x8*)(qg + headoff + (size_t)qrowA * D_ + lg * 8);
  s16x8 qfA1 = *(const s16x8*)(qg + headoff + (size_t)qrowA * D_ + 32 + lg * 8);
  s16x8 qfB0 = *(const s16x8*)(qg + headoff + (size_t)qrowB * D_ + lg * 8);
  s16x8 qfB1 = *(const s16x8*)(qg + headoff + (size_t)qrowB * D_ + 32 + lg * 8);

  f32x4 oA[4], oB[4];
#pragma unroll
  for (int n = 0; n < 4; ++n) { oA[n] = (f32x4)0.0f; oB[n] = (f32x4)0.0f; }
  float lsumA[4] = {0.f, 0.f, 0.f, 0.f};
  float lsumB[4] = {0.f, 0.f, 0.f, 0.f};
  unsigned short* psA = &Ps[wid][0][0];
  unsigned short* psB = &Ps[wid][1][0];
  const int myrowA = qtA * 64 + wid * 16 + lg * 4;
  const int myrowB = qtB * 64 + wid * 16 + lg * 4;
  const float L2E = 1.4426950408889634f;

  const unsigned short* kSrc[2];
  const unsigned short* vSrc[2];
  int dstOff[2];
#pragma unroll
  for (int i = 0; i < 2; ++i) {
    int chunk = (i * 4 + wid) * 64 + lane;
    int row = chunk >> 3, pc = chunk & 7;
    int scol = (pc ^ (row & 7)) * 8;
    kSrc[i] = Kb + (size_t)row * D_ + scol;
    vSrc[i] = Vt + (size_t)row * S_ + scol;
    dstOff[i] = (i * 4 + wid) * 1024;
  }

#pragma unroll
  for (int i = 0; i < 2; ++i) {
    GLD_LDS16(kSrc[i], (char*)Ks[0] + dstOff[i]);
    GLD_LDS16(vSrc[i], (char*)Vs[0] + dstOff[i]);
  }
  __syncthreads();

  for (int t = 0; t <= qtB; ++t) {
    const int cur = t & 1;
    const int kv0 = t * 64;
    const bool doA = (t <= qtA);
    if (t < qtB) {
      const int kvn = kv0 + 64;
#pragma unroll
      for (int i = 0; i < 2; ++i) {
        GLD_LDS16(kSrc[i] + (size_t)kvn * D_, (char*)Ks[cur ^ 1] + dstOff[i]);
        GLD_LDS16(vSrc[i] + kvn, (char*)Vs[cur ^ 1] + dstOff[i]);
      }
    }
    const unsigned short* Kc = Ks[cur];
    const unsigned short* Vc = Vs[cur];
    s16x8 kf0[4], kf1[4];
#pragma unroll
    for (int n = 0; n < 4; ++n) {
      int srow = n * 16 + l16, sw = srow & 7;
      kf0[n] = *(const s16x8*)(Kc + srow * 64 + (lg ^ sw) * 8);
      kf1[n] = *(const s16x8*)(Kc + srow * 64 + ((4 + lg) ^ sw) * 8);
    }
    f32x4 saA[4], saB[4];
    if (doA) {
#pragma unroll
      for (int n = 0; n < 4; ++n) {
        saA[n] = (f32x4)0.0f;
        saA[n] = __builtin_amdgcn_mfma_f32_16x16x32_bf16(qfA0, kf0[n], saA[n], 0, 0, 0);
        saA[n] = __builtin_amdgcn_mfma_f32_16x16x32_bf16(qfA1, kf1[n], saA[n], 0, 0, 0);
      }
    }
#pragma unroll
    for (int n = 0; n < 4; ++n) {
      saB[n] = (f32x4)0.0f;
      saB[n] = __builtin_amdgcn_mfma_f32_16x16x32_bf16(qfB0, kf0[n], saB[n], 0, 0, 0);
      saB[n] = __builtin_amdgcn_mfma_f32_16x16x32_bf16(qfB1, kf1[n], saB[n], 0, 0, 0);
    }
    if (doA) {
      const bool mask = (t == qtA);
#pragma unroll
      for (int r = 0; r < 4; ++r)
#pragma unroll
        for (int n = 0; n < 4; ++n) {
          float pv = exp2f((saA[n][r] - 12.0f) * L2E);
          if (mask && (kv0 + n * 16 + l16) > (myrowA + r)) pv = 0.0f;
          lsumA[r] += pv;
          psA[(lg * 4 + r) * 72 + n * 16 + l16] = f2bf(pv);
        }
    }
    {
      const bool mask = (t == qtB);
#pragma unroll
      for (int r = 0; r < 4; ++r)
#pragma unroll
        for (int n = 0; n < 4; ++n) {
          float pv = exp2f((saB[n][r] - 12.0f) * L2E);
          if (mask && (kv0 + n * 16 + l16) > (myrowB + r)) pv = 0.0f;
          lsumB[r] += pv;
          psB[(lg * 4 + r) * 72 + n * 16 + l16] = f2bf(pv);
        }
    }
    s16x8 vf0[4], vf1[4];
#pragma unroll
    for (int n = 0; n < 4; ++n) {
      int srow = n * 16 + l16, sw = srow & 7;
      vf0[n] = *(const s16x8*)(Vc + srow * 64 + (lg ^ sw) * 8);
      vf1[n] = *(const s16x8*)(Vc + srow * 64 + ((4 + lg) ^ sw) * 8);
    }
    __builtin_amdgcn_sched_barrier(0);
    asm volatile("s_waitcnt lgkmcnt(0)" ::: "memory");
    __builtin_amdgcn_sched_barrier(0);
    {
      s16x8 paB0 = *(const s16x8*)(psB + l16 * 72 + lg * 8);
      s16x8 paB1 = *(const s16x8*)(psB + l16 * 72 + 32 + lg * 8);
#pragma unroll
      for (int n = 0; n < 4; ++n) {
        oB[n] = __builtin_amdgcn_mfma_f32_16x16x32_bf16(paB0, vf0[n], oB[n], 0, 0, 0);
        oB[n] = __builtin_amdgcn_mfma_f32_16x16x32_bf16(paB1, vf1[n], oB[n], 0, 0, 0);
      }
      if (doA) {
        s16x8 paA0 = *(const s16x8*)(psA + l16 * 72 + lg * 8);
        s16x8 paA1 = *(const s16x8*)(psA + l16 * 72 + 32 + lg * 8);
#pragma unroll
        for (int n = 0; n < 4; ++n) {
          oA[n] = __builtin_amdgcn_mfma_f32_16x16x32_bf16(paA0, vf0[n], oA[n], 0, 0, 0);
          oA[n] = __builtin_amdgcn_mfma_f32_16x16x32_bf16(paA1, vf1[n], oA[n], 0, 0, 0);
        }
      }
    }
    __syncthreads();
  }

#pragma unroll
  for (int r = 0; r < 4; ++r) {
    float la = lsumA[r], lb = lsumB[r];
    la += __shfl_xor(la, 1); lb += __shfl_xor(lb, 1);
    la += __shfl_xor(la, 2); lb += __shfl_xor(lb, 2);
    la += __shfl_xor(la, 4); lb += __shfl_xor(lb, 4);
    la += __shfl_xor(la, 8); lb += __shfl_xor(lb, 8);
    float ia = 1.0f / la, ib = 1.0f / lb;
#pragma unroll
    for (int n = 0; n < 4; ++n) {
      ctx[headoff + (size_t)(myrowA + r) * D_ + n * 16 + l16] = f2bf(oA[n][r] * ia);
      ctx[headoff + (size_t)(myrowB + r) * D_ + n * 16 + l16] = f2bf(oB[n][r] * ib);
    }
  }
}

// ---------------- launch ----------------
extern "C" void kernel_launch(void* const* d_in, const int* in_sizes, int n_in,
                              void* d_out, int out_size, void* d_ws, size_t ws_size,
                              hipStream_t stream) {
  (void)in_sizes; (void)n_in; (void)out_size; (void)ws_size;
  const float* x   = (const float*)d_in[0];
  const float* Wq  = (const float*)d_in[1];
  const float* Wk  = (const float*)d_in[2];
  const float* Wv  = (const float*)d_in[3];
  const float* Wo  = (const float*)d_in[4];
  const float* bo  = (const float*)d_in[5];
  const float* W1  = (const float*)d_in[6];
  const float* b1  = (const float*)d_in[7];
  const float* W2  = (const float*)d_in[8];
  const float* b2  = (const float*)d_in[9];
  const float* g1  = (const float*)d_in[10];
  const float* be1 = (const float*)d_in[11];
  const float* g2  = (const float*)d_in[12];
  const float* be2 = (const float*)d_in[13];
  float* out = (float*)d_out;

  // workspace layout (136 MB): see earlier rounds
  char* w = (char*)d_ws;
  const size_t MB = 1ull << 20;
  unsigned short* wqkvT = (unsigned short*)(w + 0 * MB);
  unsigned short* woT   = (unsigned short*)(w + 6 * MB);
  unsigned short* w1T   = (unsigned short*)(w + 8 * MB);
  unsigned short* w2T   = (unsigned short*)(w + 16 * MB);
  unsigned short* hb    = (unsigned short*)(w + 24 * MB);
  float*          x2    = (float*)(w + 40 * MB);
  unsigned short* qkv   = (unsigned short*)(w + 72 * MB);   // qb | kb | vbT
  unsigned short* qb    = qkv;
  unsigned short* kb    = qkv + (size_t)MTOK * D_;
  unsigned short* vbT   = qkv + 2 * (size_t)MTOK * D_;
  unsigned short* cxb   = (unsigned short*)(w + 120 * MB);
  unsigned short* act   = (unsigned short*)(w + 72 * MB);   // aliases qkv region

  dim3 tb(32, 8);
  k_transpose<<<dim3(32, 32), tb, 0, stream>>>(Wq, wqkvT, 1024, 1024);
  k_transpose<<<dim3(32, 32), tb, 0, stream>>>(Wk, wqkvT + 1024 * 1024, 1024, 1024);
  k_transpose<<<dim3(32, 32), tb, 0, stream>>>(Wv, wqkvT + 2048 * 1024, 1024, 1024);
  k_transpose<<<dim3(32, 32), tb, 0, stream>>>(Wo, woT, 1024, 1024);
  k_transpose<<<dim3(128, 32), tb, 0, stream>>>(W1, w1T, 1024, 4096);
  k_transpose<<<dim3(32, 128), tb, 0, stream>>>(W2, w2T, 4096, 1024);

  k_layernorm<<<MTOK, 256, 0, stream>>>(x, g1, be1, hb);

  // QKV: 8-phase 256^2 -> (12, 32) = 384 blocks
  k_gemm8p<3><<<dim3(12, 32), 512, 0, stream>>>(hb, wqkvT, nullptr, qkv, MTOK, 3072, 1024);

  k_attn<<<1024, 256, 0, stream>>>(qb, kb, vbT, cxb);

  // Wo: (4, 64) = 256 blocks (r10 kernel)
  k_gemmdp<2><<<dim3(4, 64), 512, 0, stream>>>(cxb, woT, bo, x, nullptr, x2, MTOK, 1024, 1024);

  k_layernorm<<<MTOK, 256, 0, stream>>>(x2, g2, be2, hb);

  // MLP1: 8-phase 256^2 -> (16, 32) = 512 blocks
  k_gemm8p<1><<<dim3(16, 32), 512, 0, stream>>>(hb, w1T, b1, act, MTOK, 4096, 1024);
  // MLP2: (4, 64) = 256 blocks (r10 kernel)
  k_gemmdp<2><<<dim3(4, 64), 512, 0, stream>>>(act, w2T, b2, x2, nullptr, out, MTOK, 1024, 4096);
}